// Round 1
// baseline (1555.293 us; speedup 1.0000x reference)
//
#include <hip/hip_runtime.h>
#include <math.h>

#define NNODES 50000
#define NEDGES 800000
// DIM=64, EDGE_DIM=16, HEADS=4, HC=256

// ---------------- one-time prep kernels ----------------

// Fold Wa into Wn/We; transpose Wih/Whh for coalesced GRU reads.
__global__ __launch_bounds__(256) void k_fold(
    const float* __restrict__ Wn, const float* __restrict__ We,
    const float* __restrict__ Wa, const float* __restrict__ Wih,
    const float* __restrict__ Whh,
    float* __restrict__ wnwa0, float* __restrict__ wnwa2,
    float* __restrict__ wewa1, float* __restrict__ wihT, float* __restrict__ whhT)
{
    int t = threadIdx.x;
    {
        int k = t >> 2, h = t & 3;
        float s0 = 0.f, s2 = 0.f;
        for (int c = 0; c < 64; c++) {
            float wn = Wn[k * 256 + h * 64 + c];
            s0 = fmaf(wn, Wa[h * 192 + c], s0);
            s2 = fmaf(wn, Wa[h * 192 + 128 + c], s2);
        }
        wnwa0[t] = s0;
        wnwa2[t] = s2;
    }
    if (t < 64) {
        int k = t >> 2, h = t & 3;
        float s1 = 0.f;
        for (int c = 0; c < 64; c++)
            s1 = fmaf(We[k * 256 + h * 64 + c], Wa[h * 192 + 64 + c], s1);
        wewa1[t] = s1;
    }
    for (int o = t; o < 192 * 64; o += 256) {
        int k = o / 192, q = o % 192;   // wihT[k*192+q] = Wih[q][k]
        wihT[o] = Wih[q * 64 + k];
        whhT[o] = Whh[q * 64 + k];
    }
}

// ae[e][h] = edge_attr[e,:] @ wewa1[:,h]   (time-invariant)
__global__ __launch_bounds__(256) void k_ae(
    const float* __restrict__ ea, const float* __restrict__ wewa1,
    float* __restrict__ aeo)
{
    __shared__ float w[64];
    int t = threadIdx.x;
    if (t < 64) w[t] = wewa1[t];
    __syncthreads();
    int e = blockIdx.x * 256 + t;
    const float4* p = (const float4*)(ea + (size_t)e * 16);
    float4 v0 = p[0], v1 = p[1], v2 = p[2], v3 = p[3];
    float eav[16] = {v0.x, v0.y, v0.z, v0.w, v1.x, v1.y, v1.z, v1.w,
                     v2.x, v2.y, v2.z, v2.w, v3.x, v3.y, v3.z, v3.w};
    float a0 = 0.f, a1 = 0.f, a2 = 0.f, a3 = 0.f;
#pragma unroll
    for (int k = 0; k < 16; k++) {
        a0 = fmaf(eav[k], w[k * 4 + 0], a0);
        a1 = fmaf(eav[k], w[k * 4 + 1], a1);
        a2 = fmaf(eav[k], w[k * 4 + 2], a2);
        a3 = fmaf(eav[k], w[k * 4 + 3], a3);
    }
    float4 r; r.x = a0; r.y = a1; r.z = a2; r.w = a3;
    *(float4*)(aeo + (size_t)e * 4) = r;
}

__global__ __launch_bounds__(256) void k_hist(const int* __restrict__ dst, int* __restrict__ counts)
{
    int e = blockIdx.x * 256 + threadIdx.x;
    atomicAdd(&counts[dst[e]], 1);
}

__global__ __launch_bounds__(1024) void k_scan(const int* __restrict__ counts,
                                               int* __restrict__ row_ptr, int n)
{
    __shared__ int buf[1024];
    int t = threadIdx.x;
    int running = 0;
    for (int base = 0; base < n; base += 1024) {
        int idx = base + t;
        int c = (idx < n) ? counts[idx] : 0;
        buf[t] = c;
        __syncthreads();
        for (int off = 1; off < 1024; off <<= 1) {
            int v = (t >= off) ? buf[t - off] : 0;
            __syncthreads();
            buf[t] += v;
            __syncthreads();
        }
        if (idx < n) row_ptr[idx] = running + buf[t] - c;
        int tot = buf[1023];
        __syncthreads();
        running += tot;
    }
    if (t == 0) row_ptr[n] = running;
}

__global__ __launch_bounds__(256) void k_scatter(
    const int* __restrict__ srcv, const int* __restrict__ dstv,
    const int* __restrict__ row_ptr, int* __restrict__ fill,
    int* __restrict__ csr_src, int* __restrict__ csr_eid)
{
    int e = blockIdx.x * 256 + threadIdx.x;
    int d = dstv[e];
    int pos = row_ptr[d] + atomicAdd(&fill[d], 1);
    csr_src[pos] = srcv[e];
    csr_eid[pos] = e;
}

// ---------------- per-timestep kernels ----------------

// xp = xc @ Wn   [N,64]x[64,256] ; 16 nodes per 256-thread block
__global__ __launch_bounds__(256) void k_xp(
    const float* __restrict__ xc, const float* __restrict__ Wn, float* __restrict__ xp)
{
    __shared__ float xcs[16][64];
    int t = threadIdx.x;
    int nb = blockIdx.x * 16;
    {
        int g = t >> 4, k4 = t & 15;
        ((float4*)&xcs[g][0])[k4] = ((const float4*)(xc + (size_t)(nb + g) * 64))[k4];
    }
    __syncthreads();
    float acc[16];
#pragma unroll
    for (int g = 0; g < 16; g++) acc[g] = 0.f;
    for (int k = 0; k < 64; k += 4) {
        float w0 = Wn[k * 256 + t], w1 = Wn[(k + 1) * 256 + t];
        float w2 = Wn[(k + 2) * 256 + t], w3 = Wn[(k + 3) * 256 + t];
#pragma unroll
        for (int g = 0; g < 16; g++) {
            float4 xv = *(const float4*)&xcs[g][k];
            acc[g] = fmaf(xv.w, w3, fmaf(xv.z, w2, fmaf(xv.y, w1, fmaf(xv.x, w0, acc[g]))));
        }
    }
#pragma unroll
    for (int g = 0; g < 16; g++) xp[(size_t)(nb + g) * 256 + t] = acc[g];
}

// a_i/a_j per node from folded matrices: 64 nodes per block, 4 threads per node
__global__ __launch_bounds__(256) void k_aij(
    const float* __restrict__ xc, const float* __restrict__ wnwa0,
    const float* __restrict__ wnwa2, float* __restrict__ aij, int nnodes)
{
    __shared__ float w0s[256], w2s[256];
    int t = threadIdx.x;
    w0s[t] = wnwa0[t];
    w2s[t] = wnwa2[t];
    __syncthreads();
    int n = blockIdx.x * 64 + (t >> 2);
    int h = t & 3;
    if (n >= nnodes) return;
    float a_i = 0.f, a_j = 0.f;
    for (int k = 0; k < 64; k++) {
        float x = xc[(size_t)n * 64 + k];
        a_i = fmaf(x, w0s[k * 4 + h], a_i);
        a_j = fmaf(x, w2s[k * 4 + h], a_j);
    }
    aij[(size_t)n * 8 + h] = a_i;
    aij[(size_t)n * 8 + 4 + h] = a_j;
}

#define LEAKY(v) ((v) > 0.f ? (v) : 0.2f * (v))

// One wave per dst node: online softmax over its edges + weighted aggregation.
__global__ __launch_bounds__(64) void k_node(
    const int* __restrict__ row_ptr, const int* __restrict__ csr_src,
    const int* __restrict__ csr_eid, const float* __restrict__ ae,
    const float* __restrict__ aij, const float* __restrict__ xp,
    const float* __restrict__ We, const float* __restrict__ ea_g,
    float* __restrict__ aggr)
{
    __shared__ float wbuf[64][4];
    __shared__ int sbuf[64];
    __shared__ int ebuf[64];
    int n = blockIdx.x;
    int lane = threadIdx.x;
    int r0 = row_ptr[n], r1 = row_ptr[n + 1];
    float acc0 = 0.f, acc1 = 0.f, acc2 = 0.f, acc3 = 0.f;
    if (r1 > r0) {
        // per-lane We fragment: WeR[h][k] = We[k][h*64+lane]
        float WeR[4][16];
#pragma unroll
        for (int k = 0; k < 16; k++)
#pragma unroll
            for (int h = 0; h < 4; h++)
                WeR[h][k] = We[k * 256 + h * 64 + lane];
        float4 ai = *(const float4*)(aij + (size_t)n * 8);
        float m0 = -1e30f, m1 = -1e30f, m2 = -1e30f, m3 = -1e30f;
        float s0 = 0.f, s1 = 0.f, s2 = 0.f, s3 = 0.f;
        for (int base = r0; base < r1; base += 64) {
            int p = base + lane;
            if (p < r1) {
                int s = csr_src[p], eid = csr_eid[p];
                float4 a4 = *(const float4*)(ae + (size_t)eid * 4);
                float4 aj = *(const float4*)(aij + (size_t)s * 8 + 4);
                float al0 = LEAKY(ai.x + a4.x + aj.x);
                float al1 = LEAKY(ai.y + a4.y + aj.y);
                float al2 = LEAKY(ai.z + a4.z + aj.z);
                float al3 = LEAKY(ai.w + a4.w + aj.w);
                float nm;
                nm = fmaxf(m0, al0); s0 = s0 * expf(m0 - nm) + expf(al0 - nm); m0 = nm;
                nm = fmaxf(m1, al1); s1 = s1 * expf(m1 - nm) + expf(al1 - nm); m1 = nm;
                nm = fmaxf(m2, al2); s2 = s2 * expf(m2 - nm) + expf(al2 - nm); m2 = nm;
                nm = fmaxf(m3, al3); s3 = s3 * expf(m3 - nm) + expf(al3 - nm); m3 = nm;
            }
        }
        // wave-combine (m,s)
#pragma unroll
        for (int off = 32; off; off >>= 1) {
            float om, os, nm;
            om = __shfl_xor(m0, off, 64); os = __shfl_xor(s0, off, 64);
            nm = fmaxf(m0, om); s0 = s0 * expf(m0 - nm) + os * expf(om - nm); m0 = nm;
            om = __shfl_xor(m1, off, 64); os = __shfl_xor(s1, off, 64);
            nm = fmaxf(m1, om); s1 = s1 * expf(m1 - nm) + os * expf(om - nm); m1 = nm;
            om = __shfl_xor(m2, off, 64); os = __shfl_xor(s2, off, 64);
            nm = fmaxf(m2, om); s2 = s2 * expf(m2 - nm) + os * expf(om - nm); m2 = nm;
            om = __shfl_xor(m3, off, 64); os = __shfl_xor(s3, off, 64);
            nm = fmaxf(m3, om); s3 = s3 * expf(m3 - nm) + os * expf(om - nm); m3 = nm;
        }
        float rd0 = 1.f / (s0 + 1e-16f), rd1 = 1.f / (s1 + 1e-16f);
        float rd2 = 1.f / (s2 + 1e-16f), rd3 = 1.f / (s3 + 1e-16f);
        for (int base = r0; base < r1; base += 64) {
            int cnt = min(64, r1 - base);
            int p = base + lane;
            if (lane < cnt) {
                int s = csr_src[p], eid = csr_eid[p];
                float4 a4 = *(const float4*)(ae + (size_t)eid * 4);
                float4 aj = *(const float4*)(aij + (size_t)s * 8 + 4);
                float al0 = LEAKY(ai.x + a4.x + aj.x);
                float al1 = LEAKY(ai.y + a4.y + aj.y);
                float al2 = LEAKY(ai.z + a4.z + aj.z);
                float al3 = LEAKY(ai.w + a4.w + aj.w);
                wbuf[lane][0] = expf(al0 - m0) * rd0;
                wbuf[lane][1] = expf(al1 - m1) * rd1;
                wbuf[lane][2] = expf(al2 - m2) * rd2;
                wbuf[lane][3] = expf(al3 - m3) * rd3;
                sbuf[lane] = s;
                ebuf[lane] = eid;
            }
            __syncthreads();
            for (int j = 0; j < cnt; j++) {
                int s = sbuf[j], eid = ebuf[j];
                const float4* eap = (const float4*)(ea_g + (size_t)eid * 16);
                float4 e0 = eap[0], e1 = eap[1], e2 = eap[2], e3 = eap[3];
                float eav[16] = {e0.x, e0.y, e0.z, e0.w, e1.x, e1.y, e1.z, e1.w,
                                 e2.x, e2.y, e2.z, e2.w, e3.x, e3.y, e3.z, e3.w};
                float4 w4 = *(const float4*)(&wbuf[j][0]);
                const float* xprow = xp + (size_t)s * 256 + lane;
                float ep;
                ep = 0.f;
#pragma unroll
                for (int k = 0; k < 16; k++) ep = fmaf(eav[k], WeR[0][k], ep);
                acc0 = fmaf(w4.x * ep, xprow[0], acc0);
                ep = 0.f;
#pragma unroll
                for (int k = 0; k < 16; k++) ep = fmaf(eav[k], WeR[1][k], ep);
                acc1 = fmaf(w4.y * ep, xprow[64], acc1);
                ep = 0.f;
#pragma unroll
                for (int k = 0; k < 16; k++) ep = fmaf(eav[k], WeR[2][k], ep);
                acc2 = fmaf(w4.z * ep, xprow[128], acc2);
                ep = 0.f;
#pragma unroll
                for (int k = 0; k < 16; k++) ep = fmaf(eav[k], WeR[3][k], ep);
                acc3 = fmaf(w4.w * ep, xprow[192], acc3);
            }
            __syncthreads();
        }
    }
    float* ag = aggr + (size_t)n * 256 + lane;
    ag[0] = acc0; ag[64] = acc1; ag[128] = acc2; ag[192] = acc3;
}

// aggr@Ws + b -> celu -> GRU -> LayerNorm ; one wave per node
__global__ __launch_bounds__(64) void k_post(
    const float* __restrict__ aggr, const float* __restrict__ Ws,
    const float* __restrict__ bvec, const float* __restrict__ h_in,
    float* __restrict__ h_out, const float* __restrict__ wihT,
    const float* __restrict__ whhT, const float* __restrict__ bih,
    const float* __restrict__ bhh, const float* __restrict__ gamma,
    const float* __restrict__ beta, float* __restrict__ xc_out)
{
    __shared__ float agg[256];
    __shared__ float mld[64], hld[64];
    int n = blockIdx.x, j = threadIdx.x;
    *(float4*)(agg + 4 * j) = *(const float4*)(aggr + (size_t)n * 256 + 4 * j);
    float hv = h_in[(size_t)n * 64 + j];
    hld[j] = hv;
    __syncthreads();
    float out = bvec[j];
    for (int q = 0; q < 64; q++) {
        float4 a = *(const float4*)(agg + 4 * q);
        int hc = q * 4;
        out = fmaf(a.x, Ws[hc * 64 + j], out);
        out = fmaf(a.y, Ws[(hc + 1) * 64 + j], out);
        out = fmaf(a.z, Ws[(hc + 2) * 64 + j], out);
        out = fmaf(a.w, Ws[(hc + 3) * 64 + j], out);
    }
    float mv = out > 0.f ? out : expm1f(out);  // celu
    mld[j] = mv;
    __syncthreads();
    float gi0 = bih[j], gi1 = bih[64 + j], gi2 = bih[128 + j];
    float gh0 = bhh[j], gh1 = bhh[64 + j], gh2 = bhh[128 + j];
    for (int k = 0; k < 64; k++) {
        float mk = mld[k], hk = hld[k];
        const float* wi = wihT + k * 192;
        const float* wh = whhT + k * 192;
        gi0 = fmaf(mk, wi[j], gi0);
        gi1 = fmaf(mk, wi[64 + j], gi1);
        gi2 = fmaf(mk, wi[128 + j], gi2);
        gh0 = fmaf(hk, wh[j], gh0);
        gh1 = fmaf(hk, wh[64 + j], gh1);
        gh2 = fmaf(hk, wh[128 + j], gh2);
    }
    float r = 1.f / (1.f + expf(-(gi0 + gh0)));
    float z = 1.f / (1.f + expf(-(gi1 + gh1)));
    float nv = tanhf(gi2 + r * gh2);
    float hnew = (1.f - z) * nv + z * hv;
    h_out[(size_t)n * 64 + j] = hnew;
    float sum = hnew, sq = hnew * hnew;
#pragma unroll
    for (int off = 32; off; off >>= 1) {
        sum += __shfl_xor(sum, off, 64);
        sq += __shfl_xor(sq, off, 64);
    }
    float mu = sum * (1.f / 64.f);
    float var = sq * (1.f / 64.f) - mu * mu;
    float xcv = (hnew - mu) * rsqrtf(var + 1e-5f) * gamma[j] + beta[j];
    xc_out[(size_t)n * 64 + j] = xcv;
}

// ---------------- launcher ----------------

extern "C" void kernel_launch(void* const* d_in, const int* in_sizes, int n_in,
                              void* d_out, int out_size, void* d_ws, size_t ws_size,
                              hipStream_t stream)
{
    const float* x         = (const float*)d_in[0];
    const int*   edge_index= (const int*)d_in[1];
    const float* edge_attr = (const float*)d_in[2];
    const float* Wn        = (const float*)d_in[3];
    const float* We        = (const float*)d_in[4];
    const float* Wa        = (const float*)d_in[5];
    const float* Ws        = (const float*)d_in[6];
    const float* bv        = (const float*)d_in[7];
    const float* Wih       = (const float*)d_in[8];
    const float* Whh       = (const float*)d_in[9];
    const float* bih       = (const float*)d_in[10];
    const float* bhh       = (const float*)d_in[11];
    const float* gamma     = (const float*)d_in[12];
    const float* beta      = (const float*)d_in[13];
    float* out = (float*)d_out;

    const int* src = edge_index;
    const int* dst = edge_index + NEDGES;

    char* w = (char*)d_ws;
    auto alloc = [&](size_t bytes) {
        char* p = w;
        w += (bytes + 255) & ~(size_t)255;
        return p;
    };
    float* xp      = (float*)alloc((size_t)NNODES * 256 * 4);
    float* aggr    = (float*)alloc((size_t)NNODES * 256 * 4);
    float* ae      = (float*)alloc((size_t)NEDGES * 4 * 4);
    float* hbuf    = (float*)alloc((size_t)NNODES * 64 * 4);
    float* aij     = (float*)alloc((size_t)NNODES * 8 * 4);
    int*   counts  = (int*)alloc((size_t)NNODES * 4);
    int*   fill    = (int*)alloc((size_t)NNODES * 4);
    int*   row_ptr = (int*)alloc((size_t)(NNODES + 1) * 4);
    int*   csr_src = (int*)alloc((size_t)NEDGES * 4);
    int*   csr_eid = (int*)alloc((size_t)NEDGES * 4);
    float* wnwa0   = (float*)alloc(256 * 4);
    float* wnwa2   = (float*)alloc(256 * 4);
    float* wewa1   = (float*)alloc(64 * 4);
    float* wihT    = (float*)alloc(192 * 64 * 4);
    float* whhT    = (float*)alloc(192 * 64 * 4);

    k_fold<<<1, 256, 0, stream>>>(Wn, We, Wa, Wih, Whh, wnwa0, wnwa2, wewa1, wihT, whhT);
    k_ae<<<NEDGES / 256, 256, 0, stream>>>(edge_attr, wewa1, ae);
    hipMemsetAsync(counts, 0, (size_t)NNODES * 4, stream);
    hipMemsetAsync(fill, 0, (size_t)NNODES * 4, stream);
    k_hist<<<NEDGES / 256, 256, 0, stream>>>(dst, counts);
    k_scan<<<1, 1024, 0, stream>>>(counts, row_ptr, NNODES);
    k_scatter<<<NEDGES / 256, 256, 0, stream>>>(src, dst, row_ptr, fill, csr_src, csr_eid);

    for (int step = 0; step < 3; step++) {
        const float* xc_in = (step == 0) ? x : out;
        const float* h_in  = (step == 0) ? x : hbuf;
        k_xp<<<NNODES / 16, 256, 0, stream>>>(xc_in, Wn, xp);
        k_aij<<<(NNODES + 63) / 64, 256, 0, stream>>>(xc_in, wnwa0, wnwa2, aij, NNODES);
        k_node<<<NNODES, 64, 0, stream>>>(row_ptr, csr_src, csr_eid, ae, aij, xp,
                                          We, edge_attr, aggr);
        k_post<<<NNODES, 64, 0, stream>>>(aggr, Ws, bv, h_in, hbuf, wihT, whhT,
                                          bih, bhh, gamma, beta, out);
    }
}

// Round 2
// 1193.908 us; speedup vs baseline: 1.3027x; 1.3027x over previous
//
#include <hip/hip_runtime.h>
#include <math.h>

#define NNODES 50000
#define NEDGES 800000
// DIM=64, EDGE_DIM=16, HEADS=4, HC=256

// ---------------- one-time prep kernels ----------------

// Fold Wa into Wn/We; transpose Wih/Whh for coalesced GRU reads.
__global__ __launch_bounds__(256) void k_fold(
    const float* __restrict__ Wn, const float* __restrict__ We,
    const float* __restrict__ Wa, const float* __restrict__ Wih,
    const float* __restrict__ Whh,
    float* __restrict__ wnwa0, float* __restrict__ wnwa2,
    float* __restrict__ wewa1, float* __restrict__ wihT, float* __restrict__ whhT)
{
    int t = threadIdx.x;
    {
        int k = t >> 2, h = t & 3;
        float s0 = 0.f, s2 = 0.f;
        for (int c = 0; c < 64; c++) {
            float wn = Wn[k * 256 + h * 64 + c];
            s0 = fmaf(wn, Wa[h * 192 + c], s0);
            s2 = fmaf(wn, Wa[h * 192 + 128 + c], s2);
        }
        wnwa0[t] = s0;
        wnwa2[t] = s2;
    }
    if (t < 64) {
        int k = t >> 2, h = t & 3;
        float s1 = 0.f;
        for (int c = 0; c < 64; c++)
            s1 = fmaf(We[k * 256 + h * 64 + c], Wa[h * 192 + 64 + c], s1);
        wewa1[t] = s1;
    }
    for (int o = t; o < 192 * 64; o += 256) {
        int k = o / 192, q = o % 192;   // wihT[k*192+q] = Wih[q][k]
        wihT[o] = Wih[q * 64 + k];
        whhT[o] = Whh[q * 64 + k];
    }
}

// ae[e][h] = edge_attr[e,:] @ wewa1[:,h]   (time-invariant)
__global__ __launch_bounds__(256) void k_ae(
    const float* __restrict__ ea, const float* __restrict__ wewa1,
    float* __restrict__ aeo)
{
    __shared__ float w[64];
    int t = threadIdx.x;
    if (t < 64) w[t] = wewa1[t];
    __syncthreads();
    int e = blockIdx.x * 256 + t;
    const float4* p = (const float4*)(ea + (size_t)e * 16);
    float4 v0 = p[0], v1 = p[1], v2 = p[2], v3 = p[3];
    float eav[16] = {v0.x, v0.y, v0.z, v0.w, v1.x, v1.y, v1.z, v1.w,
                     v2.x, v2.y, v2.z, v2.w, v3.x, v3.y, v3.z, v3.w};
    float a0 = 0.f, a1 = 0.f, a2 = 0.f, a3 = 0.f;
#pragma unroll
    for (int k = 0; k < 16; k++) {
        a0 = fmaf(eav[k], w[k * 4 + 0], a0);
        a1 = fmaf(eav[k], w[k * 4 + 1], a1);
        a2 = fmaf(eav[k], w[k * 4 + 2], a2);
        a3 = fmaf(eav[k], w[k * 4 + 3], a3);
    }
    float4 r; r.x = a0; r.y = a1; r.z = a2; r.w = a3;
    *(float4*)(aeo + (size_t)e * 4) = r;
}

__global__ __launch_bounds__(256) void k_hist(const int* __restrict__ dst, int* __restrict__ counts)
{
    int e = blockIdx.x * 256 + threadIdx.x;
    atomicAdd(&counts[dst[e]], 1);
}

__global__ __launch_bounds__(1024) void k_scan(const int* __restrict__ counts,
                                               int* __restrict__ row_ptr, int n)
{
    __shared__ int buf[1024];
    int t = threadIdx.x;
    int running = 0;
    for (int base = 0; base < n; base += 1024) {
        int idx = base + t;
        int c = (idx < n) ? counts[idx] : 0;
        buf[t] = c;
        __syncthreads();
        for (int off = 1; off < 1024; off <<= 1) {
            int v = (t >= off) ? buf[t - off] : 0;
            __syncthreads();
            buf[t] += v;
            __syncthreads();
        }
        if (idx < n) row_ptr[idx] = running + buf[t] - c;
        int tot = buf[1023];
        __syncthreads();
        running += tot;
    }
    if (t == 0) row_ptr[n] = running;
}

__global__ __launch_bounds__(256) void k_scatter(
    const int* __restrict__ srcv, const int* __restrict__ dstv,
    const int* __restrict__ row_ptr, int* __restrict__ fill,
    int* __restrict__ csr_src, int* __restrict__ csr_eid)
{
    int e = blockIdx.x * 256 + threadIdx.x;
    int d = dstv[e];
    int pos = row_ptr[d] + atomicAdd(&fill[d], 1);
    csr_src[pos] = srcv[e];
    csr_eid[pos] = e;
}

// ---------------- per-timestep kernels ----------------

// xp = xc @ Wn   [N,64]x[64,256] ; 16 nodes per 256-thread block
__global__ __launch_bounds__(256) void k_xp(
    const float* __restrict__ xc, const float* __restrict__ Wn, float* __restrict__ xp)
{
    __shared__ float xcs[16][64];
    int t = threadIdx.x;
    int nb = blockIdx.x * 16;
    {
        int g = t >> 4, k4 = t & 15;
        ((float4*)&xcs[g][0])[k4] = ((const float4*)(xc + (size_t)(nb + g) * 64))[k4];
    }
    __syncthreads();
    float acc[16];
#pragma unroll
    for (int g = 0; g < 16; g++) acc[g] = 0.f;
    for (int k = 0; k < 64; k += 4) {
        float w0 = Wn[k * 256 + t], w1 = Wn[(k + 1) * 256 + t];
        float w2 = Wn[(k + 2) * 256 + t], w3 = Wn[(k + 3) * 256 + t];
#pragma unroll
        for (int g = 0; g < 16; g++) {
            float4 xv = *(const float4*)&xcs[g][k];
            acc[g] = fmaf(xv.w, w3, fmaf(xv.z, w2, fmaf(xv.y, w1, fmaf(xv.x, w0, acc[g]))));
        }
    }
#pragma unroll
    for (int g = 0; g < 16; g++) xp[(size_t)(nb + g) * 256 + t] = acc[g];
}

// a_i/a_j per node from folded matrices: 64 nodes per block, 4 threads per node
__global__ __launch_bounds__(256) void k_aij(
    const float* __restrict__ xc, const float* __restrict__ wnwa0,
    const float* __restrict__ wnwa2, float* __restrict__ aij, int nnodes)
{
    __shared__ float w0s[256], w2s[256];
    int t = threadIdx.x;
    w0s[t] = wnwa0[t];
    w2s[t] = wnwa2[t];
    __syncthreads();
    int n = blockIdx.x * 64 + (t >> 2);
    int h = t & 3;
    if (n >= nnodes) return;
    float a_i = 0.f, a_j = 0.f;
    for (int k = 0; k < 64; k++) {
        float x = xc[(size_t)n * 64 + k];
        a_i = fmaf(x, w0s[k * 4 + h], a_i);
        a_j = fmaf(x, w2s[k * 4 + h], a_j);
    }
    aij[(size_t)n * 8 + h] = a_i;
    aij[(size_t)n * 8 + 4 + h] = a_j;
}

#define LEAKY(v) ((v) > 0.f ? (v) : 0.2f * (v))

// One wave per dst node: online softmax over its edges + weighted aggregation.
__global__ __launch_bounds__(64) void k_node(
    const int* __restrict__ row_ptr, const int* __restrict__ csr_src,
    const int* __restrict__ csr_eid, const float* __restrict__ ae,
    const float* __restrict__ aij, const float* __restrict__ xp,
    const float* __restrict__ We, const float* __restrict__ ea_g,
    float* __restrict__ aggr)
{
    __shared__ float wbuf[64][4];
    __shared__ int sbuf[64];
    __shared__ int ebuf[64];
    int n = blockIdx.x;
    int lane = threadIdx.x;
    int r0 = row_ptr[n], r1 = row_ptr[n + 1];
    float acc0 = 0.f, acc1 = 0.f, acc2 = 0.f, acc3 = 0.f;
    if (r1 > r0) {
        // per-lane We fragment: WeR[h][k] = We[k][h*64+lane]
        float WeR[4][16];
#pragma unroll
        for (int k = 0; k < 16; k++)
#pragma unroll
            for (int h = 0; h < 4; h++)
                WeR[h][k] = We[k * 256 + h * 64 + lane];
        float4 ai = *(const float4*)(aij + (size_t)n * 8);
        float m0 = -1e30f, m1 = -1e30f, m2 = -1e30f, m3 = -1e30f;
        float s0 = 0.f, s1 = 0.f, s2 = 0.f, s3 = 0.f;
        for (int base = r0; base < r1; base += 64) {
            int p = base + lane;
            if (p < r1) {
                int s = csr_src[p], eid = csr_eid[p];
                float4 a4 = *(const float4*)(ae + (size_t)eid * 4);
                float4 aj = *(const float4*)(aij + (size_t)s * 8 + 4);
                float al0 = LEAKY(ai.x + a4.x + aj.x);
                float al1 = LEAKY(ai.y + a4.y + aj.y);
                float al2 = LEAKY(ai.z + a4.z + aj.z);
                float al3 = LEAKY(ai.w + a4.w + aj.w);
                float nm;
                nm = fmaxf(m0, al0); s0 = s0 * expf(m0 - nm) + expf(al0 - nm); m0 = nm;
                nm = fmaxf(m1, al1); s1 = s1 * expf(m1 - nm) + expf(al1 - nm); m1 = nm;
                nm = fmaxf(m2, al2); s2 = s2 * expf(m2 - nm) + expf(al2 - nm); m2 = nm;
                nm = fmaxf(m3, al3); s3 = s3 * expf(m3 - nm) + expf(al3 - nm); m3 = nm;
            }
        }
        // wave-combine (m,s)
#pragma unroll
        for (int off = 32; off; off >>= 1) {
            float om, os, nm;
            om = __shfl_xor(m0, off, 64); os = __shfl_xor(s0, off, 64);
            nm = fmaxf(m0, om); s0 = s0 * expf(m0 - nm) + os * expf(om - nm); m0 = nm;
            om = __shfl_xor(m1, off, 64); os = __shfl_xor(s1, off, 64);
            nm = fmaxf(m1, om); s1 = s1 * expf(m1 - nm) + os * expf(om - nm); m1 = nm;
            om = __shfl_xor(m2, off, 64); os = __shfl_xor(s2, off, 64);
            nm = fmaxf(m2, om); s2 = s2 * expf(m2 - nm) + os * expf(om - nm); m2 = nm;
            om = __shfl_xor(m3, off, 64); os = __shfl_xor(s3, off, 64);
            nm = fmaxf(m3, om); s3 = s3 * expf(m3 - nm) + os * expf(om - nm); m3 = nm;
        }
        float rd0 = 1.f / (s0 + 1e-16f), rd1 = 1.f / (s1 + 1e-16f);
        float rd2 = 1.f / (s2 + 1e-16f), rd3 = 1.f / (s3 + 1e-16f);
        for (int base = r0; base < r1; base += 64) {
            int cnt = min(64, r1 - base);
            int p = base + lane;
            if (lane < cnt) {
                int s = csr_src[p], eid = csr_eid[p];
                float4 a4 = *(const float4*)(ae + (size_t)eid * 4);
                float4 aj = *(const float4*)(aij + (size_t)s * 8 + 4);
                float al0 = LEAKY(ai.x + a4.x + aj.x);
                float al1 = LEAKY(ai.y + a4.y + aj.y);
                float al2 = LEAKY(ai.z + a4.z + aj.z);
                float al3 = LEAKY(ai.w + a4.w + aj.w);
                wbuf[lane][0] = expf(al0 - m0) * rd0;
                wbuf[lane][1] = expf(al1 - m1) * rd1;
                wbuf[lane][2] = expf(al2 - m2) * rd2;
                wbuf[lane][3] = expf(al3 - m3) * rd3;
                sbuf[lane] = s;
                ebuf[lane] = eid;
            }
            __syncthreads();
            for (int j = 0; j < cnt; j++) {
                int s = sbuf[j], eid = ebuf[j];
                const float4* eap = (const float4*)(ea_g + (size_t)eid * 16);
                float4 e0 = eap[0], e1 = eap[1], e2 = eap[2], e3 = eap[3];
                float eav[16] = {e0.x, e0.y, e0.z, e0.w, e1.x, e1.y, e1.z, e1.w,
                                 e2.x, e2.y, e2.z, e2.w, e3.x, e3.y, e3.z, e3.w};
                float4 w4 = *(const float4*)(&wbuf[j][0]);
                const float* xprow = xp + (size_t)s * 256 + lane;
                float ep;
                ep = 0.f;
#pragma unroll
                for (int k = 0; k < 16; k++) ep = fmaf(eav[k], WeR[0][k], ep);
                acc0 = fmaf(w4.x * ep, xprow[0], acc0);
                ep = 0.f;
#pragma unroll
                for (int k = 0; k < 16; k++) ep = fmaf(eav[k], WeR[1][k], ep);
                acc1 = fmaf(w4.y * ep, xprow[64], acc1);
                ep = 0.f;
#pragma unroll
                for (int k = 0; k < 16; k++) ep = fmaf(eav[k], WeR[2][k], ep);
                acc2 = fmaf(w4.z * ep, xprow[128], acc2);
                ep = 0.f;
#pragma unroll
                for (int k = 0; k < 16; k++) ep = fmaf(eav[k], WeR[3][k], ep);
                acc3 = fmaf(w4.w * ep, xprow[192], acc3);
            }
            __syncthreads();
        }
    }
    float* ag = aggr + (size_t)n * 256 + lane;
    ag[0] = acc0; ag[64] = acc1; ag[128] = acc2; ag[192] = acc3;
}

// aggr@Ws + b -> celu -> GRU -> LayerNorm
// 32 nodes per 256-thread block (4 waves x 8 nodes): weight loads amortized 8x
// per wave, 32x per block vs the old 1-node-per-wave version.
#define PNB 32
__global__ __launch_bounds__(256) void k_post(
    const float* __restrict__ aggr, const float* __restrict__ Ws,
    const float* __restrict__ bvec, const float* __restrict__ h_in,
    float* __restrict__ h_out, const float* __restrict__ wihT,
    const float* __restrict__ whhT, const float* __restrict__ bih,
    const float* __restrict__ bhh, const float* __restrict__ gamma,
    const float* __restrict__ beta, float* __restrict__ xc_out)
{
    __shared__ float agg[PNB][256];   // 32 KB
    __shared__ float mld[PNB][64];    // 8 KB
    __shared__ float hld[PNB][64];    // 8 KB
    int t = threadIdx.x;
    int lane = t & 63, g = t >> 6;
    int nb = blockIdx.x * PNB;
    int nrem = NNODES - nb; if (nrem > PNB) nrem = PNB;

    // stage aggr tile + h tile (coalesced float4)
    for (int i = t; i < nrem * 64; i += 256)
        ((float4*)agg)[i] = ((const float4*)(aggr + (size_t)nb * 256))[i];
    for (int i = t; i < nrem * 16; i += 256)
        ((float4*)hld)[i] = ((const float4*)(h_in + (size_t)nb * 64))[i];
    __syncthreads();

    int n0 = g * 8;  // this wave's 8 nodes
    // ---- phase 1: m = celu(aggr @ Ws + b) ----
    float bj = bvec[lane];
    float acc[8];
#pragma unroll
    for (int u = 0; u < 8; u++) acc[u] = bj;
    for (int q = 0; q < 256; q += 4) {
        float w0 = Ws[q * 64 + lane];
        float w1 = Ws[(q + 1) * 64 + lane];
        float w2 = Ws[(q + 2) * 64 + lane];
        float w3 = Ws[(q + 3) * 64 + lane];
#pragma unroll
        for (int u = 0; u < 8; u++) {
            float4 a = *(const float4*)&agg[n0 + u][q];
            acc[u] = fmaf(a.w, w3, fmaf(a.z, w2, fmaf(a.y, w1, fmaf(a.x, w0, acc[u]))));
        }
    }
#pragma unroll
    for (int u = 0; u < 8; u++)
        mld[n0 + u][lane] = acc[u] > 0.f ? acc[u] : expm1f(acc[u]);
    __syncthreads();

    // ---- phase 2: GRU gates ----
    float gi0[8], gi1[8], gi2[8], gh0[8], gh1[8], gh2[8];
    float bi0 = bih[lane], bi1 = bih[64 + lane], bi2 = bih[128 + lane];
    float bh0 = bhh[lane], bh1 = bhh[64 + lane], bh2 = bhh[128 + lane];
#pragma unroll
    for (int u = 0; u < 8; u++) {
        gi0[u] = bi0; gi1[u] = bi1; gi2[u] = bi2;
        gh0[u] = bh0; gh1[u] = bh1; gh2[u] = bh2;
    }
    for (int k = 0; k < 64; k++) {
        const float* wi = wihT + k * 192;
        const float* wh = whhT + k * 192;
        float wi0 = wi[lane], wi1 = wi[64 + lane], wi2 = wi[128 + lane];
        float wh0 = wh[lane], wh1 = wh[64 + lane], wh2 = wh[128 + lane];
#pragma unroll
        for (int u = 0; u < 8; u++) {
            float mk = mld[n0 + u][k], hk = hld[n0 + u][k];
            gi0[u] = fmaf(mk, wi0, gi0[u]);
            gi1[u] = fmaf(mk, wi1, gi1[u]);
            gi2[u] = fmaf(mk, wi2, gi2[u]);
            gh0[u] = fmaf(hk, wh0, gh0[u]);
            gh1[u] = fmaf(hk, wh1, gh1[u]);
            gh2[u] = fmaf(hk, wh2, gh2[u]);
        }
    }
    float gj = gamma[lane], btj = beta[lane];
#pragma unroll
    for (int u = 0; u < 8; u++) {
        float hv = hld[n0 + u][lane];
        float r = 1.f / (1.f + expf(-(gi0[u] + gh0[u])));
        float z = 1.f / (1.f + expf(-(gi1[u] + gh1[u])));
        float nv = tanhf(gi2[u] + r * gh2[u]);
        float hnew = (1.f - z) * nv + z * hv;
        float sum = hnew, sq = hnew * hnew;
#pragma unroll
        for (int off = 32; off; off >>= 1) {
            sum += __shfl_xor(sum, off, 64);
            sq += __shfl_xor(sq, off, 64);
        }
        float mu = sum * (1.f / 64.f);
        float var = sq * (1.f / 64.f) - mu * mu;
        float xcv = (hnew - mu) * rsqrtf(var + 1e-5f) * gj + btj;
        if (n0 + u < nrem) {
            h_out[(size_t)(nb + n0 + u) * 64 + lane] = hnew;
            xc_out[(size_t)(nb + n0 + u) * 64 + lane] = xcv;
        }
    }
}

// ---------------- launcher ----------------

extern "C" void kernel_launch(void* const* d_in, const int* in_sizes, int n_in,
                              void* d_out, int out_size, void* d_ws, size_t ws_size,
                              hipStream_t stream)
{
    const float* x         = (const float*)d_in[0];
    const int*   edge_index= (const int*)d_in[1];
    const float* edge_attr = (const float*)d_in[2];
    const float* Wn        = (const float*)d_in[3];
    const float* We        = (const float*)d_in[4];
    const float* Wa        = (const float*)d_in[5];
    const float* Ws        = (const float*)d_in[6];
    const float* bv        = (const float*)d_in[7];
    const float* Wih       = (const float*)d_in[8];
    const float* Whh       = (const float*)d_in[9];
    const float* bih       = (const float*)d_in[10];
    const float* bhh       = (const float*)d_in[11];
    const float* gamma     = (const float*)d_in[12];
    const float* beta      = (const float*)d_in[13];
    float* out = (float*)d_out;

    const int* src = edge_index;
    const int* dst = edge_index + NEDGES;

    char* w = (char*)d_ws;
    auto alloc = [&](size_t bytes) {
        char* p = w;
        w += (bytes + 255) & ~(size_t)255;
        return p;
    };
    float* xp      = (float*)alloc((size_t)NNODES * 256 * 4);
    float* aggr    = (float*)alloc((size_t)NNODES * 256 * 4);
    float* ae      = (float*)alloc((size_t)NEDGES * 4 * 4);
    float* hbuf    = (float*)alloc((size_t)NNODES * 64 * 4);
    float* aij     = (float*)alloc((size_t)NNODES * 8 * 4);
    int*   counts  = (int*)alloc((size_t)NNODES * 4);
    int*   fill    = (int*)alloc((size_t)NNODES * 4);
    int*   row_ptr = (int*)alloc((size_t)(NNODES + 1) * 4);
    int*   csr_src = (int*)alloc((size_t)NEDGES * 4);
    int*   csr_eid = (int*)alloc((size_t)NEDGES * 4);
    float* wnwa0   = (float*)alloc(256 * 4);
    float* wnwa2   = (float*)alloc(256 * 4);
    float* wewa1   = (float*)alloc(64 * 4);
    float* wihT    = (float*)alloc(192 * 64 * 4);
    float* whhT    = (float*)alloc(192 * 64 * 4);

    k_fold<<<1, 256, 0, stream>>>(Wn, We, Wa, Wih, Whh, wnwa0, wnwa2, wewa1, wihT, whhT);
    k_ae<<<NEDGES / 256, 256, 0, stream>>>(edge_attr, wewa1, ae);
    hipMemsetAsync(counts, 0, (size_t)NNODES * 4, stream);
    hipMemsetAsync(fill, 0, (size_t)NNODES * 4, stream);
    k_hist<<<NEDGES / 256, 256, 0, stream>>>(dst, counts);
    k_scan<<<1, 1024, 0, stream>>>(counts, row_ptr, NNODES);
    k_scatter<<<NEDGES / 256, 256, 0, stream>>>(src, dst, row_ptr, fill, csr_src, csr_eid);

    for (int step = 0; step < 3; step++) {
        const float* xc_in = (step == 0) ? x : out;
        const float* h_in  = (step == 0) ? x : hbuf;
        k_xp<<<NNODES / 16, 256, 0, stream>>>(xc_in, Wn, xp);
        k_aij<<<(NNODES + 63) / 64, 256, 0, stream>>>(xc_in, wnwa0, wnwa2, aij, NNODES);
        k_node<<<NNODES, 64, 0, stream>>>(row_ptr, csr_src, csr_eid, ae, aij, xp,
                                          We, edge_attr, aggr);
        k_post<<<(NNODES + PNB - 1) / PNB, 256, 0, stream>>>(
            aggr, Ws, bv, h_in, hbuf, wihT, whhT, bih, bhh, gamma, beta, out);
    }
}

// Round 3
// 1052.244 us; speedup vs baseline: 1.4781x; 1.1346x over previous
//
#include <hip/hip_runtime.h>
#include <math.h>

#define NNODES 50000
#define NEDGES 800000
// DIM=64, EDGE_DIM=16, HEADS=4, HC=256

typedef _Float16 f16;
typedef _Float16 f16x2 __attribute__((ext_vector_type(2)));

__device__ inline uint pk16(float a, float b) {
    union { f16x2 h; uint u; } c;
    c.h[0] = (f16)a; c.h[1] = (f16)b;
    return c.u;
}
__device__ inline f16x2 bc16(uint u) {
    union { uint u; f16x2 h; } c; c.u = u; return c.h;
}
__device__ inline float wred_max(float v) {
#pragma unroll
    for (int off = 32; off; off >>= 1) v = fmaxf(v, __shfl_xor(v, off, 64));
    return v;
}
__device__ inline float wred_sum(float v) {
#pragma unroll
    for (int off = 32; off; off >>= 1) v += __shfl_xor(v, off, 64);
    return v;
}

// ---------------- one-time prep kernels ----------------

// Fold Wa into Wn/We; transpose Wih/Whh; pack We into f16x2 lane fragments.
__global__ __launch_bounds__(256) void k_fold(
    const float* __restrict__ Wn, const float* __restrict__ We,
    const float* __restrict__ Wa, const float* __restrict__ Wih,
    const float* __restrict__ Whh,
    float* __restrict__ wnwa0, float* __restrict__ wnwa2,
    float* __restrict__ wewa1, float* __restrict__ wihT, float* __restrict__ whhT,
    uint* __restrict__ WeP)
{
    int t = threadIdx.x;
    {
        int k = t >> 2, h = t & 3;
        float s0 = 0.f, s2 = 0.f;
        for (int c = 0; c < 64; c++) {
            float wn = Wn[k * 256 + h * 64 + c];
            s0 = fmaf(wn, Wa[h * 192 + c], s0);
            s2 = fmaf(wn, Wa[h * 192 + 128 + c], s2);
        }
        wnwa0[t] = s0;
        wnwa2[t] = s2;
    }
    if (t < 64) {
        int k = t >> 2, h = t & 3;
        float s1 = 0.f;
        for (int c = 0; c < 64; c++)
            s1 = fmaf(We[k * 256 + h * 64 + c], Wa[h * 192 + 64 + c], s1);
        wewa1[t] = s1;
    }
    for (int o = t; o < 192 * 64; o += 256) {
        int k = o / 192, q = o % 192;   // wihT[k*192+q] = Wih[q][k]
        wihT[o] = Wih[q * 64 + k];
        whhT[o] = Whh[q * 64 + k];
    }
    // WeP[(h*8+jp)*64 + lane] = pack(We[2jp][h*64+lane], We[2jp+1][h*64+lane])
    for (int idx = t; idx < 2048; idx += 256) {
        int h = idx >> 9, rem = idx & 511;
        int jp = rem >> 6, lane = rem & 63;
        int c = h * 64 + lane, k0 = 2 * jp;
        WeP[idx] = pk16(We[k0 * 256 + c], We[(k0 + 1) * 256 + c]);
    }
}

// ae[e][h] = edge_attr[e,:] @ wewa1[:,h]  +  pack edge_attr to f16 (32B/edge)
__global__ __launch_bounds__(256) void k_ae(
    const float* __restrict__ ea, const float* __restrict__ wewa1,
    float* __restrict__ aeo, uint* __restrict__ ea16)
{
    __shared__ float w[64];
    int t = threadIdx.x;
    if (t < 64) w[t] = wewa1[t];
    __syncthreads();
    int e = blockIdx.x * 256 + t;
    const float4* p = (const float4*)(ea + (size_t)e * 16);
    float4 v0 = p[0], v1 = p[1], v2 = p[2], v3 = p[3];
    float eav[16] = {v0.x, v0.y, v0.z, v0.w, v1.x, v1.y, v1.z, v1.w,
                     v2.x, v2.y, v2.z, v2.w, v3.x, v3.y, v3.z, v3.w};
    float a0 = 0.f, a1 = 0.f, a2 = 0.f, a3 = 0.f;
#pragma unroll
    for (int k = 0; k < 16; k++) {
        a0 = fmaf(eav[k], w[k * 4 + 0], a0);
        a1 = fmaf(eav[k], w[k * 4 + 1], a1);
        a2 = fmaf(eav[k], w[k * 4 + 2], a2);
        a3 = fmaf(eav[k], w[k * 4 + 3], a3);
    }
    float4 r; r.x = a0; r.y = a1; r.z = a2; r.w = a3;
    *(float4*)(aeo + (size_t)e * 4) = r;
    uint4 pa, pb;
    pa.x = pk16(eav[0], eav[1]);  pa.y = pk16(eav[2], eav[3]);
    pa.z = pk16(eav[4], eav[5]);  pa.w = pk16(eav[6], eav[7]);
    pb.x = pk16(eav[8], eav[9]);  pb.y = pk16(eav[10], eav[11]);
    pb.z = pk16(eav[12], eav[13]); pb.w = pk16(eav[14], eav[15]);
    uint4* o16 = (uint4*)(ea16 + (size_t)e * 8);
    o16[0] = pa; o16[1] = pb;
}

__global__ __launch_bounds__(256) void k_hist(const int* __restrict__ dst, int* __restrict__ counts)
{
    int e = blockIdx.x * 256 + threadIdx.x;
    atomicAdd(&counts[dst[e]], 1);
}

__global__ __launch_bounds__(1024) void k_scan(const int* __restrict__ counts,
                                               int* __restrict__ row_ptr, int n)
{
    __shared__ int buf[1024];
    int t = threadIdx.x;
    int running = 0;
    for (int base = 0; base < n; base += 1024) {
        int idx = base + t;
        int c = (idx < n) ? counts[idx] : 0;
        buf[t] = c;
        __syncthreads();
        for (int off = 1; off < 1024; off <<= 1) {
            int v = (t >= off) ? buf[t - off] : 0;
            __syncthreads();
            buf[t] += v;
            __syncthreads();
        }
        if (idx < n) row_ptr[idx] = running + buf[t] - c;
        int tot = buf[1023];
        __syncthreads();
        running += tot;
    }
    if (t == 0) row_ptr[n] = running;
}

// Build CSR: src index + ae + packed f16 edge_attr, all in CSR order.
__global__ __launch_bounds__(256) void k_scatter(
    const int* __restrict__ srcv, const int* __restrict__ dstv,
    const int* __restrict__ row_ptr, int* __restrict__ fill,
    const float* __restrict__ ae, const uint* __restrict__ ea16,
    int* __restrict__ csr_src, float* __restrict__ ae_csr,
    uint* __restrict__ ea16_csr)
{
    int e = blockIdx.x * 256 + threadIdx.x;
    int d = dstv[e];
    int pos = row_ptr[d] + atomicAdd(&fill[d], 1);
    csr_src[pos] = srcv[e];
    *(float4*)(ae_csr + (size_t)pos * 4) = *(const float4*)(ae + (size_t)e * 4);
    const uint4* s16 = (const uint4*)(ea16 + (size_t)e * 8);
    uint4 a = s16[0], b = s16[1];
    uint4* d16 = (uint4*)(ea16_csr + (size_t)pos * 8);
    d16[0] = a; d16[1] = b;
}

// ---------------- per-timestep kernels ----------------

// xp16 = f16(xc @ Wn)   [N,64]x[64,256] ; 16 nodes per 256-thread block
__global__ __launch_bounds__(256) void k_xp(
    const float* __restrict__ xc, const float* __restrict__ Wn, f16* __restrict__ xp16)
{
    __shared__ float xcs[16][64];
    int t = threadIdx.x;
    int nb = blockIdx.x * 16;
    {
        int g = t >> 4, k4 = t & 15;
        ((float4*)&xcs[g][0])[k4] = ((const float4*)(xc + (size_t)(nb + g) * 64))[k4];
    }
    __syncthreads();
    float acc[16];
#pragma unroll
    for (int g = 0; g < 16; g++) acc[g] = 0.f;
    for (int k = 0; k < 64; k += 4) {
        float w0 = Wn[k * 256 + t], w1 = Wn[(k + 1) * 256 + t];
        float w2 = Wn[(k + 2) * 256 + t], w3 = Wn[(k + 3) * 256 + t];
#pragma unroll
        for (int g = 0; g < 16; g++) {
            float4 xv = *(const float4*)&xcs[g][k];
            acc[g] = fmaf(xv.w, w3, fmaf(xv.z, w2, fmaf(xv.y, w1, fmaf(xv.x, w0, acc[g]))));
        }
    }
#pragma unroll
    for (int g = 0; g < 16; g++) xp16[(size_t)(nb + g) * 256 + t] = (f16)acc[g];
}

// a_i/a_j per node, split output arrays (denser gather tables)
__global__ __launch_bounds__(256) void k_aij(
    const float* __restrict__ xc, const float* __restrict__ wnwa0,
    const float* __restrict__ wnwa2, float* __restrict__ aijI,
    float* __restrict__ aijJ, int nnodes)
{
    __shared__ float w0s[256], w2s[256];
    int t = threadIdx.x;
    w0s[t] = wnwa0[t];
    w2s[t] = wnwa2[t];
    __syncthreads();
    int n = blockIdx.x * 64 + (t >> 2);
    int h = t & 3;
    if (n >= nnodes) return;
    float a_i = 0.f, a_j = 0.f;
    for (int k = 0; k < 64; k++) {
        float x = xc[(size_t)n * 64 + k];
        a_i = fmaf(x, w0s[k * 4 + h], a_i);
        a_j = fmaf(x, w2s[k * 4 + h], a_j);
    }
    aijI[(size_t)n * 4 + h] = a_i;
    aijJ[(size_t)n * 4 + h] = a_j;
}

#define LEAKY(v) ((v) > 0.f ? (v) : 0.2f * (v))

// Softmax + aggregation: one wave per dst node, 4 nodes per 256-thread block.
// Fast path (deg<=64, ~all nodes with Poisson(16)): softmax in registers.
// No __syncthreads (waves independent); per-wave LDS staging fenced with
// explicit s_waitcnt lgkmcnt(0).
__global__ __launch_bounds__(256) void k_node(
    const int* __restrict__ row_ptr, const int* __restrict__ csr_src,
    const float* __restrict__ ae_csr, const float* __restrict__ aijI,
    const float* __restrict__ aijJ, const f16* __restrict__ xp16,
    const uint* __restrict__ ea16_csr, const uint* __restrict__ WeP,
    float* __restrict__ aggr)
{
    __shared__ float wbuf[4][64][4];
    int t = threadIdx.x, wid = t >> 6, lane = t & 63;
    int n = blockIdx.x * 4 + wid;
    // per-lane packed We fragments: wep[h][jp] covers channel h*64+lane, k=2jp..2jp+1
    f16x2 wep[4][8];
#pragma unroll
    for (int h = 0; h < 4; h++)
#pragma unroll
        for (int jp = 0; jp < 8; jp++)
            wep[h][jp] = bc16(WeP[(h * 8 + jp) * 64 + lane]);
    int r0 = row_ptr[n], r1 = row_ptr[n + 1];
    int deg = r1 - r0;
    float acc0 = 0.f, acc1 = 0.f, acc2 = 0.f, acc3 = 0.f;

    auto agg_edge = [&](int pos, int sj, const float4& w4) {
        const uint4* eap = (const uint4*)(ea16_csr + (size_t)pos * 8);
        uint4 u0 = eap[0], u1 = eap[1];
        f16x2 e0 = bc16(u0.x), e1 = bc16(u0.y), e2 = bc16(u0.z), e3 = bc16(u0.w);
        f16x2 e4 = bc16(u1.x), e5 = bc16(u1.y), e6 = bc16(u1.z), e7 = bc16(u1.w);
        const f16* xr = xp16 + (size_t)sj * 256 + lane;
        float ep;
        ep = __builtin_amdgcn_fdot2(e0, wep[0][0], 0.f, false);
        ep = __builtin_amdgcn_fdot2(e1, wep[0][1], ep, false);
        ep = __builtin_amdgcn_fdot2(e2, wep[0][2], ep, false);
        ep = __builtin_amdgcn_fdot2(e3, wep[0][3], ep, false);
        ep = __builtin_amdgcn_fdot2(e4, wep[0][4], ep, false);
        ep = __builtin_amdgcn_fdot2(e5, wep[0][5], ep, false);
        ep = __builtin_amdgcn_fdot2(e6, wep[0][6], ep, false);
        ep = __builtin_amdgcn_fdot2(e7, wep[0][7], ep, false);
        acc0 = fmaf(w4.x * ep, (float)xr[0], acc0);
        ep = __builtin_amdgcn_fdot2(e0, wep[1][0], 0.f, false);
        ep = __builtin_amdgcn_fdot2(e1, wep[1][1], ep, false);
        ep = __builtin_amdgcn_fdot2(e2, wep[1][2], ep, false);
        ep = __builtin_amdgcn_fdot2(e3, wep[1][3], ep, false);
        ep = __builtin_amdgcn_fdot2(e4, wep[1][4], ep, false);
        ep = __builtin_amdgcn_fdot2(e5, wep[1][5], ep, false);
        ep = __builtin_amdgcn_fdot2(e6, wep[1][6], ep, false);
        ep = __builtin_amdgcn_fdot2(e7, wep[1][7], ep, false);
        acc1 = fmaf(w4.y * ep, (float)xr[64], acc1);
        ep = __builtin_amdgcn_fdot2(e0, wep[2][0], 0.f, false);
        ep = __builtin_amdgcn_fdot2(e1, wep[2][1], ep, false);
        ep = __builtin_amdgcn_fdot2(e2, wep[2][2], ep, false);
        ep = __builtin_amdgcn_fdot2(e3, wep[2][3], ep, false);
        ep = __builtin_amdgcn_fdot2(e4, wep[2][4], ep, false);
        ep = __builtin_amdgcn_fdot2(e5, wep[2][5], ep, false);
        ep = __builtin_amdgcn_fdot2(e6, wep[2][6], ep, false);
        ep = __builtin_amdgcn_fdot2(e7, wep[2][7], ep, false);
        acc2 = fmaf(w4.z * ep, (float)xr[128], acc2);
        ep = __builtin_amdgcn_fdot2(e0, wep[3][0], 0.f, false);
        ep = __builtin_amdgcn_fdot2(e1, wep[3][1], ep, false);
        ep = __builtin_amdgcn_fdot2(e2, wep[3][2], ep, false);
        ep = __builtin_amdgcn_fdot2(e3, wep[3][3], ep, false);
        ep = __builtin_amdgcn_fdot2(e4, wep[3][4], ep, false);
        ep = __builtin_amdgcn_fdot2(e5, wep[3][5], ep, false);
        ep = __builtin_amdgcn_fdot2(e6, wep[3][6], ep, false);
        ep = __builtin_amdgcn_fdot2(e7, wep[3][7], ep, false);
        acc3 = fmaf(w4.w * ep, (float)xr[192], acc3);
    };

    if (deg > 0 && deg <= 64) {
        float4 ai = *(const float4*)(aijI + (size_t)n * 4);
        float al0 = -1e30f, al1 = -1e30f, al2 = -1e30f, al3 = -1e30f;
        int sreg = 0;
        if (lane < deg) {
            int p = r0 + lane;
            sreg = csr_src[p];
            float4 a4 = *(const float4*)(ae_csr + (size_t)p * 4);
            float4 aj = *(const float4*)(aijJ + (size_t)sreg * 4);
            al0 = LEAKY(ai.x + a4.x + aj.x);
            al1 = LEAKY(ai.y + a4.y + aj.y);
            al2 = LEAKY(ai.z + a4.z + aj.z);
            al3 = LEAKY(ai.w + a4.w + aj.w);
        }
        float m0 = wred_max(al0), m1 = wred_max(al1);
        float m2 = wred_max(al2), m3 = wred_max(al3);
        float p0 = (lane < deg) ? __expf(al0 - m0) : 0.f;
        float p1 = (lane < deg) ? __expf(al1 - m1) : 0.f;
        float p2 = (lane < deg) ? __expf(al2 - m2) : 0.f;
        float p3 = (lane < deg) ? __expf(al3 - m3) : 0.f;
        float s0 = wred_sum(p0), s1 = wred_sum(p1);
        float s2 = wred_sum(p2), s3 = wred_sum(p3);
        float4 w4v;
        w4v.x = p0 * (1.f / (s0 + 1e-16f));
        w4v.y = p1 * (1.f / (s1 + 1e-16f));
        w4v.z = p2 * (1.f / (s2 + 1e-16f));
        w4v.w = p3 * (1.f / (s3 + 1e-16f));
        *(float4*)&wbuf[wid][lane][0] = w4v;
        asm volatile("s_waitcnt lgkmcnt(0)" ::: "memory");
        for (int j = 0; j < deg; j++) {
            int sj = __shfl(sreg, j, 64);
            float4 w4 = *(const float4*)&wbuf[wid][j][0];
            agg_edge(r0 + j, sj, w4);
        }
    } else if (deg > 0) {
        // generic slow path (deg > 64): online softmax over 64-edge batches
        float4 ai = *(const float4*)(aijI + (size_t)n * 4);
        float m0 = -1e30f, m1 = -1e30f, m2 = -1e30f, m3 = -1e30f;
        float s0 = 0.f, s1 = 0.f, s2 = 0.f, s3 = 0.f;
        for (int base = r0; base < r1; base += 64) {
            int p = base + lane;
            if (p < r1) {
                int s = csr_src[p];
                float4 a4 = *(const float4*)(ae_csr + (size_t)p * 4);
                float4 aj = *(const float4*)(aijJ + (size_t)s * 4);
                float al0 = LEAKY(ai.x + a4.x + aj.x);
                float al1 = LEAKY(ai.y + a4.y + aj.y);
                float al2 = LEAKY(ai.z + a4.z + aj.z);
                float al3 = LEAKY(ai.w + a4.w + aj.w);
                float nm;
                nm = fmaxf(m0, al0); s0 = s0 * __expf(m0 - nm) + __expf(al0 - nm); m0 = nm;
                nm = fmaxf(m1, al1); s1 = s1 * __expf(m1 - nm) + __expf(al1 - nm); m1 = nm;
                nm = fmaxf(m2, al2); s2 = s2 * __expf(m2 - nm) + __expf(al2 - nm); m2 = nm;
                nm = fmaxf(m3, al3); s3 = s3 * __expf(m3 - nm) + __expf(al3 - nm); m3 = nm;
            }
        }
#pragma unroll
        for (int off = 32; off; off >>= 1) {
            float om, os, nm;
            om = __shfl_xor(m0, off, 64); os = __shfl_xor(s0, off, 64);
            nm = fmaxf(m0, om); s0 = s0 * __expf(m0 - nm) + os * __expf(om - nm); m0 = nm;
            om = __shfl_xor(m1, off, 64); os = __shfl_xor(s1, off, 64);
            nm = fmaxf(m1, om); s1 = s1 * __expf(m1 - nm) + os * __expf(om - nm); m1 = nm;
            om = __shfl_xor(m2, off, 64); os = __shfl_xor(s2, off, 64);
            nm = fmaxf(m2, om); s2 = s2 * __expf(m2 - nm) + os * __expf(om - nm); m2 = nm;
            om = __shfl_xor(m3, off, 64); os = __shfl_xor(s3, off, 64);
            nm = fmaxf(m3, om); s3 = s3 * __expf(m3 - nm) + os * __expf(om - nm); m3 = nm;
        }
        float rd0 = 1.f / (s0 + 1e-16f), rd1 = 1.f / (s1 + 1e-16f);
        float rd2 = 1.f / (s2 + 1e-16f), rd3 = 1.f / (s3 + 1e-16f);
        for (int base = r0; base < r1; base += 64) {
            int cnt = min(64, r1 - base);
            int sreg = 0;
            if (lane < cnt) {
                int p = base + lane;
                sreg = csr_src[p];
                float4 a4 = *(const float4*)(ae_csr + (size_t)p * 4);
                float4 aj = *(const float4*)(aijJ + (size_t)sreg * 4);
                float al0 = LEAKY(ai.x + a4.x + aj.x);
                float al1 = LEAKY(ai.y + a4.y + aj.y);
                float al2 = LEAKY(ai.z + a4.z + aj.z);
                float al3 = LEAKY(ai.w + a4.w + aj.w);
                float4 w4v;
                w4v.x = __expf(al0 - m0) * rd0;
                w4v.y = __expf(al1 - m1) * rd1;
                w4v.z = __expf(al2 - m2) * rd2;
                w4v.w = __expf(al3 - m3) * rd3;
                *(float4*)&wbuf[wid][lane][0] = w4v;
            }
            asm volatile("s_waitcnt lgkmcnt(0)" ::: "memory");
            for (int j = 0; j < cnt; j++) {
                int sj = __shfl(sreg, j, 64);
                float4 w4 = *(const float4*)&wbuf[wid][j][0];
                agg_edge(base + j, sj, w4);
            }
            asm volatile("s_waitcnt lgkmcnt(0)" ::: "memory");
        }
    }
    float* ag = aggr + (size_t)n * 256 + lane;
    ag[0] = acc0; ag[64] = acc1; ag[128] = acc2; ag[192] = acc3;
}

// aggr@Ws + b -> celu -> GRU -> LayerNorm ; 32 nodes per 256-thread block
#define PNB 32
__global__ __launch_bounds__(256) void k_post(
    const float* __restrict__ aggr, const float* __restrict__ Ws,
    const float* __restrict__ bvec, const float* __restrict__ h_in,
    float* __restrict__ h_out, const float* __restrict__ wihT,
    const float* __restrict__ whhT, const float* __restrict__ bih,
    const float* __restrict__ bhh, const float* __restrict__ gamma,
    const float* __restrict__ beta, float* __restrict__ xc_out)
{
    __shared__ float agg[PNB][256];   // 32 KB
    __shared__ float mld[PNB][64];    // 8 KB
    __shared__ float hld[PNB][64];    // 8 KB
    int t = threadIdx.x;
    int lane = t & 63, g = t >> 6;
    int nb = blockIdx.x * PNB;
    int nrem = NNODES - nb; if (nrem > PNB) nrem = PNB;

    for (int i = t; i < nrem * 64; i += 256)
        ((float4*)agg)[i] = ((const float4*)(aggr + (size_t)nb * 256))[i];
    for (int i = t; i < nrem * 16; i += 256)
        ((float4*)hld)[i] = ((const float4*)(h_in + (size_t)nb * 64))[i];
    __syncthreads();

    int n0 = g * 8;
    float bj = bvec[lane];
    float acc[8];
#pragma unroll
    for (int u = 0; u < 8; u++) acc[u] = bj;
    for (int q = 0; q < 256; q += 4) {
        float w0 = Ws[q * 64 + lane];
        float w1 = Ws[(q + 1) * 64 + lane];
        float w2 = Ws[(q + 2) * 64 + lane];
        float w3 = Ws[(q + 3) * 64 + lane];
#pragma unroll
        for (int u = 0; u < 8; u++) {
            float4 a = *(const float4*)&agg[n0 + u][q];
            acc[u] = fmaf(a.w, w3, fmaf(a.z, w2, fmaf(a.y, w1, fmaf(a.x, w0, acc[u]))));
        }
    }
#pragma unroll
    for (int u = 0; u < 8; u++)
        mld[n0 + u][lane] = acc[u] > 0.f ? acc[u] : expm1f(acc[u]);
    __syncthreads();

    float gi0[8], gi1[8], gi2[8], gh0[8], gh1[8], gh2[8];
    float bi0 = bih[lane], bi1 = bih[64 + lane], bi2 = bih[128 + lane];
    float bh0 = bhh[lane], bh1 = bhh[64 + lane], bh2 = bhh[128 + lane];
#pragma unroll
    for (int u = 0; u < 8; u++) {
        gi0[u] = bi0; gi1[u] = bi1; gi2[u] = bi2;
        gh0[u] = bh0; gh1[u] = bh1; gh2[u] = bh2;
    }
    for (int k = 0; k < 64; k++) {
        const float* wi = wihT + k * 192;
        const float* wh = whhT + k * 192;
        float wi0 = wi[lane], wi1 = wi[64 + lane], wi2 = wi[128 + lane];
        float wh0 = wh[lane], wh1 = wh[64 + lane], wh2 = wh[128 + lane];
#pragma unroll
        for (int u = 0; u < 8; u++) {
            float mk = mld[n0 + u][k], hk = hld[n0 + u][k];
            gi0[u] = fmaf(mk, wi0, gi0[u]);
            gi1[u] = fmaf(mk, wi1, gi1[u]);
            gi2[u] = fmaf(mk, wi2, gi2[u]);
            gh0[u] = fmaf(hk, wh0, gh0[u]);
            gh1[u] = fmaf(hk, wh1, gh1[u]);
            gh2[u] = fmaf(hk, wh2, gh2[u]);
        }
    }
    float gj = gamma[lane], btj = beta[lane];
#pragma unroll
    for (int u = 0; u < 8; u++) {
        float hv = hld[n0 + u][lane];
        float r = 1.f / (1.f + expf(-(gi0[u] + gh0[u])));
        float z = 1.f / (1.f + expf(-(gi1[u] + gh1[u])));
        float nv = tanhf(gi2[u] + r * gh2[u]);
        float hnew = (1.f - z) * nv + z * hv;
        float sum = hnew, sq = hnew * hnew;
#pragma unroll
        for (int off = 32; off; off >>= 1) {
            sum += __shfl_xor(sum, off, 64);
            sq += __shfl_xor(sq, off, 64);
        }
        float mu = sum * (1.f / 64.f);
        float var = sq * (1.f / 64.f) - mu * mu;
        float xcv = (hnew - mu) * rsqrtf(var + 1e-5f) * gj + btj;
        if (n0 + u < nrem) {
            h_out[(size_t)(nb + n0 + u) * 64 + lane] = hnew;
            xc_out[(size_t)(nb + n0 + u) * 64 + lane] = xcv;
        }
    }
}

// ---------------- launcher ----------------

extern "C" void kernel_launch(void* const* d_in, const int* in_sizes, int n_in,
                              void* d_out, int out_size, void* d_ws, size_t ws_size,
                              hipStream_t stream)
{
    const float* x         = (const float*)d_in[0];
    const int*   edge_index= (const int*)d_in[1];
    const float* edge_attr = (const float*)d_in[2];
    const float* Wn        = (const float*)d_in[3];
    const float* We        = (const float*)d_in[4];
    const float* Wa        = (const float*)d_in[5];
    const float* Ws        = (const float*)d_in[6];
    const float* bv        = (const float*)d_in[7];
    const float* Wih       = (const float*)d_in[8];
    const float* Whh       = (const float*)d_in[9];
    const float* bih       = (const float*)d_in[10];
    const float* bhh       = (const float*)d_in[11];
    const float* gamma     = (const float*)d_in[12];
    const float* beta      = (const float*)d_in[13];
    float* out = (float*)d_out;

    const int* src = edge_index;
    const int* dst = edge_index + NEDGES;

    char* w = (char*)d_ws;
    auto alloc = [&](size_t bytes) {
        char* p = w;
        w += (bytes + 255) & ~(size_t)255;
        return p;
    };
    f16*   xp16     = (f16*)alloc((size_t)NNODES * 256 * 2);
    float* aggr     = (float*)alloc((size_t)NNODES * 256 * 4);
    float* ae       = (float*)alloc((size_t)NEDGES * 4 * 4);
    float* ae_csr   = (float*)alloc((size_t)NEDGES * 4 * 4);
    uint*  ea16     = (uint*)alloc((size_t)NEDGES * 8 * 4);
    uint*  ea16_csr = (uint*)alloc((size_t)NEDGES * 8 * 4);
    float* hbuf     = (float*)alloc((size_t)NNODES * 64 * 4);
    float* aijI     = (float*)alloc((size_t)NNODES * 4 * 4);
    float* aijJ     = (float*)alloc((size_t)NNODES * 4 * 4);
    int*   counts   = (int*)alloc((size_t)NNODES * 4);
    int*   fill     = (int*)alloc((size_t)NNODES * 4);
    int*   row_ptr  = (int*)alloc((size_t)(NNODES + 1) * 4);
    int*   csr_src  = (int*)alloc((size_t)NEDGES * 4);
    float* wnwa0    = (float*)alloc(256 * 4);
    float* wnwa2    = (float*)alloc(256 * 4);
    float* wewa1    = (float*)alloc(64 * 4);
    float* wihT     = (float*)alloc(192 * 64 * 4);
    float* whhT     = (float*)alloc(192 * 64 * 4);
    uint*  WeP      = (uint*)alloc(2048 * 4);

    k_fold<<<1, 256, 0, stream>>>(Wn, We, Wa, Wih, Whh, wnwa0, wnwa2, wewa1,
                                  wihT, whhT, WeP);
    k_ae<<<NEDGES / 256, 256, 0, stream>>>(edge_attr, wewa1, ae, ea16);
    hipMemsetAsync(counts, 0, (size_t)NNODES * 4, stream);
    hipMemsetAsync(fill, 0, (size_t)NNODES * 4, stream);
    k_hist<<<NEDGES / 256, 256, 0, stream>>>(dst, counts);
    k_scan<<<1, 1024, 0, stream>>>(counts, row_ptr, NNODES);
    k_scatter<<<NEDGES / 256, 256, 0, stream>>>(src, dst, row_ptr, fill,
                                                ae, ea16, csr_src, ae_csr, ea16_csr);

    for (int step = 0; step < 3; step++) {
        const float* xc_in = (step == 0) ? x : out;
        const float* h_in  = (step == 0) ? x : hbuf;
        k_xp<<<NNODES / 16, 256, 0, stream>>>(xc_in, Wn, xp16);
        k_aij<<<(NNODES + 63) / 64, 256, 0, stream>>>(xc_in, wnwa0, wnwa2,
                                                      aijI, aijJ, NNODES);
        k_node<<<NNODES / 4, 256, 0, stream>>>(row_ptr, csr_src, ae_csr, aijI,
                                               aijJ, xp16, ea16_csr, WeP, aggr);
        k_post<<<(NNODES + PNB - 1) / PNB, 256, 0, stream>>>(
            aggr, Ws, bv, h_in, hbuf, wihT, whhT, bih, bhh, gamma, beta, out);
    }
}

// Round 4
// 986.826 us; speedup vs baseline: 1.5761x; 1.0663x over previous
//
#include <hip/hip_runtime.h>
#include <math.h>

#define NNODES 50000
#define NEDGES 800000
// DIM=64, EDGE_DIM=16, HEADS=4, HC=256

typedef _Float16 f16;
typedef _Float16 f16x2 __attribute__((ext_vector_type(2)));

__device__ inline uint pk16(float a, float b) {
    union { f16x2 h; uint u; } c;
    c.h[0] = (f16)a; c.h[1] = (f16)b;
    return c.u;
}
__device__ inline f16x2 bc16(uint u) {
    union { uint u; f16x2 h; } c; c.u = u; return c.h;
}
__device__ inline float wred_max(float v) {
#pragma unroll
    for (int off = 32; off; off >>= 1) v = fmaxf(v, __shfl_xor(v, off, 64));
    return v;
}
__device__ inline float wred_sum(float v) {
#pragma unroll
    for (int off = 32; off; off >>= 1) v += __shfl_xor(v, off, 64);
    return v;
}

// ---------------- one-time prep kernels ----------------

// Fold Wa into Wn/We; transpose Wih/Whh; pack We into f16x2 lane fragments.
__global__ __launch_bounds__(256) void k_fold(
    const float* __restrict__ Wn, const float* __restrict__ We,
    const float* __restrict__ Wa, const float* __restrict__ Wih,
    const float* __restrict__ Whh,
    float* __restrict__ wnwa0, float* __restrict__ wnwa2,
    float* __restrict__ wewa1, float* __restrict__ wihT, float* __restrict__ whhT,
    uint* __restrict__ WeP)
{
    int t = threadIdx.x;
    {
        int k = t >> 2, h = t & 3;
        float s0 = 0.f, s2 = 0.f;
        for (int c = 0; c < 64; c++) {
            float wn = Wn[k * 256 + h * 64 + c];
            s0 = fmaf(wn, Wa[h * 192 + c], s0);
            s2 = fmaf(wn, Wa[h * 192 + 128 + c], s2);
        }
        wnwa0[t] = s0;
        wnwa2[t] = s2;
    }
    if (t < 64) {
        int k = t >> 2, h = t & 3;
        float s1 = 0.f;
        for (int c = 0; c < 64; c++)
            s1 = fmaf(We[k * 256 + h * 64 + c], Wa[h * 192 + 64 + c], s1);
        wewa1[t] = s1;
    }
    for (int o = t; o < 192 * 64; o += 256) {
        int k = o / 192, q = o % 192;   // wihT[k*192+q] = Wih[q][k]
        wihT[o] = Wih[q * 64 + k];
        whhT[o] = Whh[q * 64 + k];
    }
    // WeP[(h*8+jp)*64 + lane] = pack(We[2jp][h*64+lane], We[2jp+1][h*64+lane])
    for (int idx = t; idx < 2048; idx += 256) {
        int h = idx >> 9, rem = idx & 511;
        int jp = rem >> 6, lane = rem & 63;
        int c = h * 64 + lane, k0 = 2 * jp;
        WeP[idx] = pk16(We[k0 * 256 + c], We[(k0 + 1) * 256 + c]);
    }
}

// ae[e][h] = edge_attr[e,:] @ wewa1[:,h]  +  pack edge_attr to f16 (32B/edge)
__global__ __launch_bounds__(256) void k_ae(
    const float* __restrict__ ea, const float* __restrict__ wewa1,
    float* __restrict__ aeo, uint* __restrict__ ea16)
{
    __shared__ float w[64];
    int t = threadIdx.x;
    if (t < 64) w[t] = wewa1[t];
    __syncthreads();
    int e = blockIdx.x * 256 + t;
    const float4* p = (const float4*)(ea + (size_t)e * 16);
    float4 v0 = p[0], v1 = p[1], v2 = p[2], v3 = p[3];
    float eav[16] = {v0.x, v0.y, v0.z, v0.w, v1.x, v1.y, v1.z, v1.w,
                     v2.x, v2.y, v2.z, v2.w, v3.x, v3.y, v3.z, v3.w};
    float a0 = 0.f, a1 = 0.f, a2 = 0.f, a3 = 0.f;
#pragma unroll
    for (int k = 0; k < 16; k++) {
        a0 = fmaf(eav[k], w[k * 4 + 0], a0);
        a1 = fmaf(eav[k], w[k * 4 + 1], a1);
        a2 = fmaf(eav[k], w[k * 4 + 2], a2);
        a3 = fmaf(eav[k], w[k * 4 + 3], a3);
    }
    float4 r; r.x = a0; r.y = a1; r.z = a2; r.w = a3;
    *(float4*)(aeo + (size_t)e * 4) = r;
    uint4 pa, pb;
    pa.x = pk16(eav[0], eav[1]);  pa.y = pk16(eav[2], eav[3]);
    pa.z = pk16(eav[4], eav[5]);  pa.w = pk16(eav[6], eav[7]);
    pb.x = pk16(eav[8], eav[9]);  pb.y = pk16(eav[10], eav[11]);
    pb.z = pk16(eav[12], eav[13]); pb.w = pk16(eav[14], eav[15]);
    uint4* o16 = (uint4*)(ea16 + (size_t)e * 8);
    o16[0] = pa; o16[1] = pb;
}

__global__ __launch_bounds__(256) void k_hist(const int* __restrict__ dst, int* __restrict__ counts)
{
    int e = blockIdx.x * 256 + threadIdx.x;
    atomicAdd(&counts[dst[e]], 1);
}

// shfl-based scan: 2 syncthreads per 1024-chunk (old version used ~20)
__global__ __launch_bounds__(1024) void k_scan(const int* __restrict__ counts,
                                               int* __restrict__ row_ptr, int n)
{
    __shared__ int wsum[16];
    int t = threadIdx.x, wid = t >> 6, lane = t & 63;
    int running = 0;
    for (int base = 0; base < n; base += 1024) {
        int idx = base + t;
        int c = (idx < n) ? counts[idx] : 0;
        int v = c;
#pragma unroll
        for (int off = 1; off < 64; off <<= 1) {
            int u = __shfl_up(v, off, 64);
            if (lane >= off) v += u;
        }
        if (lane == 63) wsum[wid] = v;
        __syncthreads();
        int wpre = 0, tot = 0;
#pragma unroll
        for (int wk = 0; wk < 16; wk++) {
            int s = wsum[wk];
            if (wk < wid) wpre += s;
            tot += s;
        }
        if (idx < n) row_ptr[idx] = running + wpre + v - c;  // exclusive
        running += tot;
        __syncthreads();
    }
    if (t == 0) row_ptr[n] = running;
}

// Build CSR: src index + ae + packed f16 edge_attr, all in CSR order.
__global__ __launch_bounds__(256) void k_scatter(
    const int* __restrict__ srcv, const int* __restrict__ dstv,
    const int* __restrict__ row_ptr, int* __restrict__ fill,
    const float* __restrict__ ae, const uint* __restrict__ ea16,
    int* __restrict__ csr_src, float* __restrict__ ae_csr,
    uint* __restrict__ ea16_csr)
{
    int e = blockIdx.x * 256 + threadIdx.x;
    int d = dstv[e];
    int pos = row_ptr[d] + atomicAdd(&fill[d], 1);
    csr_src[pos] = srcv[e];
    *(float4*)(ae_csr + (size_t)pos * 4) = *(const float4*)(ae + (size_t)e * 4);
    const uint4* s16 = (const uint4*)(ea16 + (size_t)e * 8);
    uint4 a = s16[0], b = s16[1];
    uint4* d16 = (uint4*)(ea16_csr + (size_t)pos * 8);
    d16[0] = a; d16[1] = b;
}

// ---------------- per-timestep kernels ----------------

// xp16 = f16(xc @ Wn), HEAD-INTERLEAVED layout: xp16[n*256 + lane*4 + h]
// (one dwordx2 per lane covers all 4 heads of a node row in k_node)
__global__ __launch_bounds__(256) void k_xp(
    const float* __restrict__ xc, const float* __restrict__ Wn, f16* __restrict__ xp16)
{
    __shared__ float xcs[16][64];
    int t = threadIdx.x;
    int nb = blockIdx.x * 16;
    {
        int g = t >> 4, k4 = t & 15;
        ((float4*)&xcs[g][0])[k4] = ((const float4*)(xc + (size_t)(nb + g) * 64))[k4];
    }
    __syncthreads();
    float acc[16];
#pragma unroll
    for (int g = 0; g < 16; g++) acc[g] = 0.f;
    for (int k = 0; k < 64; k += 4) {
        float w0 = Wn[k * 256 + t], w1 = Wn[(k + 1) * 256 + t];
        float w2 = Wn[(k + 2) * 256 + t], w3 = Wn[(k + 3) * 256 + t];
#pragma unroll
        for (int g = 0; g < 16; g++) {
            float4 xv = *(const float4*)&xcs[g][k];
            acc[g] = fmaf(xv.w, w3, fmaf(xv.z, w2, fmaf(xv.y, w1, fmaf(xv.x, w0, acc[g]))));
        }
    }
    int h = t >> 6, lane = t & 63;
#pragma unroll
    for (int g = 0; g < 16; g++)
        xp16[(size_t)(nb + g) * 256 + lane * 4 + h] = (f16)acc[g];
}

// a_i/a_j per node, split output arrays (denser gather tables)
__global__ __launch_bounds__(256) void k_aij(
    const float* __restrict__ xc, const float* __restrict__ wnwa0,
    const float* __restrict__ wnwa2, float* __restrict__ aijI,
    float* __restrict__ aijJ, int nnodes)
{
    __shared__ float w0s[256], w2s[256];
    int t = threadIdx.x;
    w0s[t] = wnwa0[t];
    w2s[t] = wnwa2[t];
    __syncthreads();
    int n = blockIdx.x * 64 + (t >> 2);
    int h = t & 3;
    if (n >= nnodes) return;
    float a_i = 0.f, a_j = 0.f;
    for (int k = 0; k < 64; k++) {
        float x = xc[(size_t)n * 64 + k];
        a_i = fmaf(x, w0s[k * 4 + h], a_i);
        a_j = fmaf(x, w2s[k * 4 + h], a_j);
    }
    aijI[(size_t)n * 4 + h] = a_i;
    aijJ[(size_t)n * 4 + h] = a_j;
}

#define LEAKY(v) ((v) > 0.f ? (v) : 0.2f * (v))

// Softmax + aggregation: one wave per dst node, 4 nodes per 256-thread block.
// ea16 staged in LDS during softmax phase; per-edge gather is ONE dwordx2.
// Depth-2 software pipeline on the xj gathers (named regs, no dyn indexing).
__global__ __launch_bounds__(256) void k_node(
    const int* __restrict__ row_ptr, const int* __restrict__ csr_src,
    const float* __restrict__ ae_csr, const float* __restrict__ aijI,
    const float* __restrict__ aijJ, const f16* __restrict__ xp16,
    const uint* __restrict__ ea16_csr, const uint* __restrict__ WeP,
    float* __restrict__ aggr)
{
    __shared__ float wbuf[4][64][4];   // 4 KB
    __shared__ uint  eabuf[4][64][8];  // 8 KB
    int t = threadIdx.x, wid = t >> 6, lane = t & 63;
    int n = blockIdx.x * 4 + wid;
    // per-lane packed We fragments: wep[h][jp] covers channel h*64+lane, k=2jp..2jp+1
    f16x2 wep[4][8];
#pragma unroll
    for (int h = 0; h < 4; h++)
#pragma unroll
        for (int jp = 0; jp < 8; jp++)
            wep[h][jp] = bc16(WeP[(h * 8 + jp) * 64 + lane]);
    int r0 = row_ptr[n], r1 = row_ptr[n + 1];
    int deg = r1 - r0;
    float acc0 = 0.f, acc1 = 0.f, acc2 = 0.f, acc3 = 0.f;
    uint loff = (uint)lane << 2;

    // compute one edge from LDS-staged data + preloaded xj (uint2 of 4 f16)
    auto agg_edge = [&](int j, uint2 xu) {
        float4 w4 = *(const float4*)&wbuf[wid][j][0];
        const uint4* eb = (const uint4*)&eabuf[wid][j][0];
        uint4 u0 = eb[0], u1 = eb[1];
        f16x2 e0 = bc16(u0.x), e1 = bc16(u0.y), e2 = bc16(u0.z), e3 = bc16(u0.w);
        f16x2 e4 = bc16(u1.x), e5 = bc16(u1.y), e6 = bc16(u1.z), e7 = bc16(u1.w);
        f16x2 x01 = bc16(xu.x), x23 = bc16(xu.y);
        float ep0, ep1, ep2, ep3;
        ep0 = __builtin_amdgcn_fdot2(e0, wep[0][0], 0.f, false);
        ep1 = __builtin_amdgcn_fdot2(e0, wep[1][0], 0.f, false);
        ep2 = __builtin_amdgcn_fdot2(e0, wep[2][0], 0.f, false);
        ep3 = __builtin_amdgcn_fdot2(e0, wep[3][0], 0.f, false);
        ep0 = __builtin_amdgcn_fdot2(e1, wep[0][1], ep0, false);
        ep1 = __builtin_amdgcn_fdot2(e1, wep[1][1], ep1, false);
        ep2 = __builtin_amdgcn_fdot2(e1, wep[2][1], ep2, false);
        ep3 = __builtin_amdgcn_fdot2(e1, wep[3][1], ep3, false);
        ep0 = __builtin_amdgcn_fdot2(e2, wep[0][2], ep0, false);
        ep1 = __builtin_amdgcn_fdot2(e2, wep[1][2], ep1, false);
        ep2 = __builtin_amdgcn_fdot2(e2, wep[2][2], ep2, false);
        ep3 = __builtin_amdgcn_fdot2(e2, wep[3][2], ep3, false);
        ep0 = __builtin_amdgcn_fdot2(e3, wep[0][3], ep0, false);
        ep1 = __builtin_amdgcn_fdot2(e3, wep[1][3], ep1, false);
        ep2 = __builtin_amdgcn_fdot2(e3, wep[2][3], ep2, false);
        ep3 = __builtin_amdgcn_fdot2(e3, wep[3][3], ep3, false);
        ep0 = __builtin_amdgcn_fdot2(e4, wep[0][4], ep0, false);
        ep1 = __builtin_amdgcn_fdot2(e4, wep[1][4], ep1, false);
        ep2 = __builtin_amdgcn_fdot2(e4, wep[2][4], ep2, false);
        ep3 = __builtin_amdgcn_fdot2(e4, wep[3][4], ep3, false);
        ep0 = __builtin_amdgcn_fdot2(e5, wep[0][5], ep0, false);
        ep1 = __builtin_amdgcn_fdot2(e5, wep[1][5], ep1, false);
        ep2 = __builtin_amdgcn_fdot2(e5, wep[2][5], ep2, false);
        ep3 = __builtin_amdgcn_fdot2(e5, wep[3][5], ep3, false);
        ep0 = __builtin_amdgcn_fdot2(e6, wep[0][6], ep0, false);
        ep1 = __builtin_amdgcn_fdot2(e6, wep[1][6], ep1, false);
        ep2 = __builtin_amdgcn_fdot2(e6, wep[2][6], ep2, false);
        ep3 = __builtin_amdgcn_fdot2(e6, wep[3][6], ep3, false);
        ep0 = __builtin_amdgcn_fdot2(e7, wep[0][7], ep0, false);
        ep1 = __builtin_amdgcn_fdot2(e7, wep[1][7], ep1, false);
        ep2 = __builtin_amdgcn_fdot2(e7, wep[2][7], ep2, false);
        ep3 = __builtin_amdgcn_fdot2(e7, wep[3][7], ep3, false);
        acc0 = fmaf(w4.x * ep0, (float)x01[0], acc0);
        acc1 = fmaf(w4.y * ep1, (float)x01[1], acc1);
        acc2 = fmaf(w4.z * ep2, (float)x23[0], acc2);
        acc3 = fmaf(w4.w * ep3, (float)x23[1], acc3);
    };
    auto xload = [&](int sj) {
        return *(const uint2*)(xp16 + (((uint)sj << 8) + loff));
    };

    if (deg > 0 && deg <= 64) {
        float4 ai = *(const float4*)(aijI + (size_t)n * 4);
        float al0 = -1e30f, al1 = -1e30f, al2 = -1e30f, al3 = -1e30f;
        int sreg = 0;
        if (lane < deg) {
            int p = r0 + lane;
            sreg = csr_src[p];
            float4 a4 = *(const float4*)(ae_csr + (size_t)p * 4);
            float4 aj = *(const float4*)(aijJ + (size_t)sreg * 4);
            const uint4* ep16 = (const uint4*)(ea16_csr + (size_t)p * 8);
            uint4 ua = ep16[0], ub = ep16[1];
            *(uint4*)&eabuf[wid][lane][0] = ua;
            *(uint4*)&eabuf[wid][lane][4] = ub;
            al0 = LEAKY(ai.x + a4.x + aj.x);
            al1 = LEAKY(ai.y + a4.y + aj.y);
            al2 = LEAKY(ai.z + a4.z + aj.z);
            al3 = LEAKY(ai.w + a4.w + aj.w);
        }
        float m0 = wred_max(al0), m1 = wred_max(al1);
        float m2 = wred_max(al2), m3 = wred_max(al3);
        float p0 = (lane < deg) ? __expf(al0 - m0) : 0.f;
        float p1 = (lane < deg) ? __expf(al1 - m1) : 0.f;
        float p2 = (lane < deg) ? __expf(al2 - m2) : 0.f;
        float p3 = (lane < deg) ? __expf(al3 - m3) : 0.f;
        float s0 = wred_sum(p0), s1 = wred_sum(p1);
        float s2 = wred_sum(p2), s3 = wred_sum(p3);
        float4 w4v;
        w4v.x = p0 * (1.f / (s0 + 1e-16f));
        w4v.y = p1 * (1.f / (s1 + 1e-16f));
        w4v.z = p2 * (1.f / (s2 + 1e-16f));
        w4v.w = p3 * (1.f / (s3 + 1e-16f));
        *(float4*)&wbuf[wid][lane][0] = w4v;
        asm volatile("s_waitcnt lgkmcnt(0)" ::: "memory");
        // depth-2 pipelined gather loop
        int sjA = __shfl(sreg, 0, 64);
        int sjB = __shfl(sreg, 1, 64);
        uint2 xa = xload(sjA);
        uint2 xb = (deg > 1) ? xload(sjB) : xa;
        int j = 0;
        for (; j + 1 < deg; j += 2) {
            int sj2 = __shfl(sreg, j + 2, 64);
            int sj3 = __shfl(sreg, j + 3, 64);
            uint2 xac = xa, xbc = xb;
            if (j + 2 < deg) xa = xload(sj2);
            if (j + 3 < deg) xb = xload(sj3);
            agg_edge(j, xac);
            agg_edge(j + 1, xbc);
        }
        if (j < deg) agg_edge(j, xa);
    } else if (deg > 0) {
        // generic slow path (deg > 64): online softmax over 64-edge batches
        float4 ai = *(const float4*)(aijI + (size_t)n * 4);
        float m0 = -1e30f, m1 = -1e30f, m2 = -1e30f, m3 = -1e30f;
        float s0 = 0.f, s1 = 0.f, s2 = 0.f, s3 = 0.f;
        for (int base = r0; base < r1; base += 64) {
            int p = base + lane;
            if (p < r1) {
                int s = csr_src[p];
                float4 a4 = *(const float4*)(ae_csr + (size_t)p * 4);
                float4 aj = *(const float4*)(aijJ + (size_t)s * 4);
                float al0 = LEAKY(ai.x + a4.x + aj.x);
                float al1 = LEAKY(ai.y + a4.y + aj.y);
                float al2 = LEAKY(ai.z + a4.z + aj.z);
                float al3 = LEAKY(ai.w + a4.w + aj.w);
                float nm;
                nm = fmaxf(m0, al0); s0 = s0 * __expf(m0 - nm) + __expf(al0 - nm); m0 = nm;
                nm = fmaxf(m1, al1); s1 = s1 * __expf(m1 - nm) + __expf(al1 - nm); m1 = nm;
                nm = fmaxf(m2, al2); s2 = s2 * __expf(m2 - nm) + __expf(al2 - nm); m2 = nm;
                nm = fmaxf(m3, al3); s3 = s3 * __expf(m3 - nm) + __expf(al3 - nm); m3 = nm;
            }
        }
#pragma unroll
        for (int off = 32; off; off >>= 1) {
            float om, os, nm;
            om = __shfl_xor(m0, off, 64); os = __shfl_xor(s0, off, 64);
            nm = fmaxf(m0, om); s0 = s0 * __expf(m0 - nm) + os * __expf(om - nm); m0 = nm;
            om = __shfl_xor(m1, off, 64); os = __shfl_xor(s1, off, 64);
            nm = fmaxf(m1, om); s1 = s1 * __expf(m1 - nm) + os * __expf(om - nm); m1 = nm;
            om = __shfl_xor(m2, off, 64); os = __shfl_xor(s2, off, 64);
            nm = fmaxf(m2, om); s2 = s2 * __expf(m2 - nm) + os * __expf(om - nm); m2 = nm;
            om = __shfl_xor(m3, off, 64); os = __shfl_xor(s3, off, 64);
            nm = fmaxf(m3, om); s3 = s3 * __expf(m3 - nm) + os * __expf(om - nm); m3 = nm;
        }
        float rd0 = 1.f / (s0 + 1e-16f), rd1 = 1.f / (s1 + 1e-16f);
        float rd2 = 1.f / (s2 + 1e-16f), rd3 = 1.f / (s3 + 1e-16f);
        for (int base = r0; base < r1; base += 64) {
            int cnt = min(64, r1 - base);
            int sreg = 0;
            if (lane < cnt) {
                int p = base + lane;
                sreg = csr_src[p];
                float4 a4 = *(const float4*)(ae_csr + (size_t)p * 4);
                float4 aj = *(const float4*)(aijJ + (size_t)sreg * 4);
                const uint4* ep16 = (const uint4*)(ea16_csr + (size_t)p * 8);
                uint4 ua = ep16[0], ub = ep16[1];
                *(uint4*)&eabuf[wid][lane][0] = ua;
                *(uint4*)&eabuf[wid][lane][4] = ub;
                float al0 = LEAKY(ai.x + a4.x + aj.x);
                float al1 = LEAKY(ai.y + a4.y + aj.y);
                float al2 = LEAKY(ai.z + a4.z + aj.z);
                float al3 = LEAKY(ai.w + a4.w + aj.w);
                float4 w4v;
                w4v.x = __expf(al0 - m0) * rd0;
                w4v.y = __expf(al1 - m1) * rd1;
                w4v.z = __expf(al2 - m2) * rd2;
                w4v.w = __expf(al3 - m3) * rd3;
                *(float4*)&wbuf[wid][lane][0] = w4v;
            }
            asm volatile("s_waitcnt lgkmcnt(0)" ::: "memory");
            for (int j = 0; j < cnt; j++) {
                int sj = __shfl(sreg, j, 64);
                agg_edge(j, xload(sj));
            }
            asm volatile("s_waitcnt lgkmcnt(0)" ::: "memory");
        }
    }
    float* ag = aggr + (size_t)n * 256 + lane;
    ag[0] = acc0; ag[64] = acc1; ag[128] = acc2; ag[192] = acc3;
}

// aggr@Ws + b -> celu -> GRU -> LayerNorm ; 32 nodes per 256-thread block
// NOTE: aggr rows are in (lane,head)-natural order h*64+lane (matches Ws rows
// hc = h*64+lane? no — aggr[n*256 + h*64 + lane] with channel hc = h*64+lane,
// identical to original layout; k_node writes ag[0/64/128/192] at +lane).
#define PNB 32
__global__ __launch_bounds__(256) void k_post(
    const float* __restrict__ aggr, const float* __restrict__ Ws,
    const float* __restrict__ bvec, const float* __restrict__ h_in,
    float* __restrict__ h_out, const float* __restrict__ wihT,
    const float* __restrict__ whhT, const float* __restrict__ bih,
    const float* __restrict__ bhh, const float* __restrict__ gamma,
    const float* __restrict__ beta, float* __restrict__ xc_out)
{
    __shared__ float agg[PNB][256];   // 32 KB
    __shared__ float mld[PNB][64];    // 8 KB
    __shared__ float hld[PNB][64];    // 8 KB
    int t = threadIdx.x;
    int lane = t & 63, g = t >> 6;
    int nb = blockIdx.x * PNB;
    int nrem = NNODES - nb; if (nrem > PNB) nrem = PNB;

    for (int i = t; i < nrem * 64; i += 256)
        ((float4*)agg)[i] = ((const float4*)(aggr + (size_t)nb * 256))[i];
    for (int i = t; i < nrem * 16; i += 256)
        ((float4*)hld)[i] = ((const float4*)(h_in + (size_t)nb * 64))[i];
    __syncthreads();

    int n0 = g * 8;
    float bj = bvec[lane];
    float acc[8];
#pragma unroll
    for (int u = 0; u < 8; u++) acc[u] = bj;
    for (int q = 0; q < 256; q += 4) {
        float w0 = Ws[q * 64 + lane];
        float w1 = Ws[(q + 1) * 64 + lane];
        float w2 = Ws[(q + 2) * 64 + lane];
        float w3 = Ws[(q + 3) * 64 + lane];
#pragma unroll
        for (int u = 0; u < 8; u++) {
            float4 a = *(const float4*)&agg[n0 + u][q];
            acc[u] = fmaf(a.w, w3, fmaf(a.z, w2, fmaf(a.y, w1, fmaf(a.x, w0, acc[u]))));
        }
    }
#pragma unroll
    for (int u = 0; u < 8; u++)
        mld[n0 + u][lane] = acc[u] > 0.f ? acc[u] : expm1f(acc[u]);
    __syncthreads();

    float gi0[8], gi1[8], gi2[8], gh0[8], gh1[8], gh2[8];
    float bi0 = bih[lane], bi1 = bih[64 + lane], bi2 = bih[128 + lane];
    float bh0 = bhh[lane], bh1 = bhh[64 + lane], bh2 = bhh[128 + lane];
#pragma unroll
    for (int u = 0; u < 8; u++) {
        gi0[u] = bi0; gi1[u] = bi1; gi2[u] = bi2;
        gh0[u] = bh0; gh1[u] = bh1; gh2[u] = bh2;
    }
    for (int k = 0; k < 64; k++) {
        const float* wi = wihT + k * 192;
        const float* wh = whhT + k * 192;
        float wi0 = wi[lane], wi1 = wi[64 + lane], wi2 = wi[128 + lane];
        float wh0 = wh[lane], wh1 = wh[64 + lane], wh2 = wh[128 + lane];
#pragma unroll
        for (int u = 0; u < 8; u++) {
            float mk = mld[n0 + u][k], hk = hld[n0 + u][k];
            gi0[u] = fmaf(mk, wi0, gi0[u]);
            gi1[u] = fmaf(mk, wi1, gi1[u]);
            gi2[u] = fmaf(mk, wi2, gi2[u]);
            gh0[u] = fmaf(hk, wh0, gh0[u]);
            gh1[u] = fmaf(hk, wh1, gh1[u]);
            gh2[u] = fmaf(hk, wh2, gh2[u]);
        }
    }
    float gj = gamma[lane], btj = beta[lane];
#pragma unroll
    for (int u = 0; u < 8; u++) {
        float hv = hld[n0 + u][lane];
        float r = 1.f / (1.f + expf(-(gi0[u] + gh0[u])));
        float z = 1.f / (1.f + expf(-(gi1[u] + gh1[u])));
        float nv = tanhf(gi2[u] + r * gh2[u]);
        float hnew = (1.f - z) * nv + z * hv;
        float sum = hnew, sq = hnew * hnew;
#pragma unroll
        for (int off = 32; off; off >>= 1) {
            sum += __shfl_xor(sum, off, 64);
            sq += __shfl_xor(sq, off, 64);
        }
        float mu = sum * (1.f / 64.f);
        float var = sq * (1.f / 64.f) - mu * mu;
        float xcv = (hnew - mu) * rsqrtf(var + 1e-5f) * gj + btj;
        if (n0 + u < nrem) {
            h_out[(size_t)(nb + n0 + u) * 64 + lane] = hnew;
            xc_out[(size_t)(nb + n0 + u) * 64 + lane] = xcv;
        }
    }
}

// ---------------- launcher ----------------

extern "C" void kernel_launch(void* const* d_in, const int* in_sizes, int n_in,
                              void* d_out, int out_size, void* d_ws, size_t ws_size,
                              hipStream_t stream)
{
    const float* x         = (const float*)d_in[0];
    const int*   edge_index= (const int*)d_in[1];
    const float* edge_attr = (const float*)d_in[2];
    const float* Wn        = (const float*)d_in[3];
    const float* We        = (const float*)d_in[4];
    const float* Wa        = (const float*)d_in[5];
    const float* Ws        = (const float*)d_in[6];
    const float* bv        = (const float*)d_in[7];
    const float* Wih       = (const float*)d_in[8];
    const float* Whh       = (const float*)d_in[9];
    const float* bih       = (const float*)d_in[10];
    const float* bhh       = (const float*)d_in[11];
    const float* gamma     = (const float*)d_in[12];
    const float* beta      = (const float*)d_in[13];
    float* out = (float*)d_out;

    const int* src = edge_index;
    const int* dst = edge_index + NEDGES;

    char* w = (char*)d_ws;
    auto alloc = [&](size_t bytes) {
        char* p = w;
        w += (bytes + 255) & ~(size_t)255;
        return p;
    };
    f16*   xp16     = (f16*)alloc((size_t)NNODES * 256 * 2);
    float* aggr     = (float*)alloc((size_t)NNODES * 256 * 4);
    float* ae       = (float*)alloc((size_t)NEDGES * 4 * 4);
    float* ae_csr   = (float*)alloc((size_t)NEDGES * 4 * 4);
    uint*  ea16     = (uint*)alloc((size_t)NEDGES * 8 * 4);
    uint*  ea16_csr = (uint*)alloc((size_t)NEDGES * 8 * 4);
    float* hbuf     = (float*)alloc((size_t)NNODES * 64 * 4);
    float* aijI     = (float*)alloc((size_t)NNODES * 4 * 4);
    float* aijJ     = (float*)alloc((size_t)NNODES * 4 * 4);
    int*   counts   = (int*)alloc((size_t)NNODES * 4);
    int*   fill     = (int*)alloc((size_t)NNODES * 4);
    int*   row_ptr  = (int*)alloc((size_t)(NNODES + 1) * 4);
    int*   csr_src  = (int*)alloc((size_t)NEDGES * 4);
    float* wnwa0    = (float*)alloc(256 * 4);
    float* wnwa2    = (float*)alloc(256 * 4);
    float* wewa1    = (float*)alloc(64 * 4);
    float* wihT     = (float*)alloc(192 * 64 * 4);
    float* whhT     = (float*)alloc(192 * 64 * 4);
    uint*  WeP      = (uint*)alloc(2048 * 4);

    k_fold<<<1, 256, 0, stream>>>(Wn, We, Wa, Wih, Whh, wnwa0, wnwa2, wewa1,
                                  wihT, whhT, WeP);
    k_ae<<<NEDGES / 256, 256, 0, stream>>>(edge_attr, wewa1, ae, ea16);
    hipMemsetAsync(counts, 0, (size_t)NNODES * 4, stream);
    hipMemsetAsync(fill, 0, (size_t)NNODES * 4, stream);
    k_hist<<<NEDGES / 256, 256, 0, stream>>>(dst, counts);
    k_scan<<<1, 1024, 0, stream>>>(counts, row_ptr, NNODES);
    k_scatter<<<NEDGES / 256, 256, 0, stream>>>(src, dst, row_ptr, fill,
                                                ae, ea16, csr_src, ae_csr, ea16_csr);

    for (int step = 0; step < 3; step++) {
        const float* xc_in = (step == 0) ? x : out;
        const float* h_in  = (step == 0) ? x : hbuf;
        k_xp<<<NNODES / 16, 256, 0, stream>>>(xc_in, Wn, xp16);
        k_aij<<<(NNODES + 63) / 64, 256, 0, stream>>>(xc_in, wnwa0, wnwa2,
                                                      aijI, aijJ, NNODES);
        k_node<<<NNODES / 4, 256, 0, stream>>>(row_ptr, csr_src, ae_csr, aijI,
                                               aijJ, xp16, ea16_csr, WeP, aggr);
        k_post<<<(NNODES + PNB - 1) / PNB, 256, 0, stream>>>(
            aggr, Ws, bv, h_in, hbuf, wihT, whhT, bih, bhh, gamma, beta, out);
    }
}

// Round 5
// 908.820 us; speedup vs baseline: 1.7113x; 1.0858x over previous
//
#include <hip/hip_runtime.h>
#include <math.h>

#define NNODES 50000
#define NEDGES 800000
// DIM=64, EDGE_DIM=16, HEADS=4, HC=256

typedef _Float16 f16;
typedef _Float16 f16x2 __attribute__((ext_vector_type(2)));

__device__ inline uint pk16(float a, float b) {
    union { f16x2 h; uint u; } c;
    c.h[0] = (f16)a; c.h[1] = (f16)b;
    return c.u;
}
__device__ inline f16x2 bc16(uint u) {
    union { uint u; f16x2 h; } c; c.u = u; return c.h;
}
__device__ inline float wred_max(float v) {
#pragma unroll
    for (int off = 32; off; off >>= 1) v = fmaxf(v, __shfl_xor(v, off, 64));
    return v;
}
__device__ inline float wred_sum(float v) {
#pragma unroll
    for (int off = 32; off; off >>= 1) v += __shfl_xor(v, off, 64);
    return v;
}

// ---------------- one-time prep kernels ----------------

// Fold Wa into Wn/We; transpose Wih/Whh; pack We into f16x2 lane fragments.
__global__ __launch_bounds__(256) void k_fold(
    const float* __restrict__ Wn, const float* __restrict__ We,
    const float* __restrict__ Wa, const float* __restrict__ Wih,
    const float* __restrict__ Whh,
    float* __restrict__ wnwa0, float* __restrict__ wnwa2,
    float* __restrict__ wewa1, float* __restrict__ wihT, float* __restrict__ whhT,
    uint* __restrict__ WeP)
{
    int t = threadIdx.x;
    {
        int k = t >> 2, h = t & 3;
        float s0 = 0.f, s2 = 0.f;
        for (int c = 0; c < 64; c++) {
            float wn = Wn[k * 256 + h * 64 + c];
            s0 = fmaf(wn, Wa[h * 192 + c], s0);
            s2 = fmaf(wn, Wa[h * 192 + 128 + c], s2);
        }
        wnwa0[t] = s0;
        wnwa2[t] = s2;
    }
    if (t < 64) {
        int k = t >> 2, h = t & 3;
        float s1 = 0.f;
        for (int c = 0; c < 64; c++)
            s1 = fmaf(We[k * 256 + h * 64 + c], Wa[h * 192 + 64 + c], s1);
        wewa1[t] = s1;
    }
    for (int o = t; o < 192 * 64; o += 256) {
        int k = o / 192, q = o % 192;   // wihT[k*192+q] = Wih[q][k]
        wihT[o] = Wih[q * 64 + k];
        whhT[o] = Whh[q * 64 + k];
    }
    // WeP[(h*8+jp)*64 + lane] = pack(We[2jp][h*64+lane], We[2jp+1][h*64+lane])
    for (int idx = t; idx < 2048; idx += 256) {
        int h = idx >> 9, rem = idx & 511;
        int jp = rem >> 6, lane = rem & 63;
        int c = h * 64 + lane, k0 = 2 * jp;
        WeP[idx] = pk16(We[k0 * 256 + c], We[(k0 + 1) * 256 + c]);
    }
}

__global__ __launch_bounds__(256) void k_hist(const int* __restrict__ dst, int* __restrict__ counts)
{
    int e = blockIdx.x * 256 + threadIdx.x;
    atomicAdd(&counts[dst[e]], 1);
}

// shfl-based scan: 2 syncthreads per 1024-chunk
__global__ __launch_bounds__(1024) void k_scan(const int* __restrict__ counts,
                                               int* __restrict__ row_ptr, int n)
{
    __shared__ int wsum[16];
    int t = threadIdx.x, wid = t >> 6, lane = t & 63;
    int running = 0;
    for (int base = 0; base < n; base += 1024) {
        int idx = base + t;
        int c = (idx < n) ? counts[idx] : 0;
        int v = c;
#pragma unroll
        for (int off = 1; off < 64; off <<= 1) {
            int u = __shfl_up(v, off, 64);
            if (lane >= off) v += u;
        }
        if (lane == 63) wsum[wid] = v;
        __syncthreads();
        int wpre = 0, tot = 0;
#pragma unroll
        for (int wk = 0; wk < 16; wk++) {
            int s = wsum[wk];
            if (wk < wid) wpre += s;
            tot += s;
        }
        if (idx < n) row_ptr[idx] = running + wpre + v - c;  // exclusive
        running += tot;
        __syncthreads();
    }
    if (t == 0) row_ptr[n] = running;
}

// Build CSR with fused ae compute + f16 pack (k_ae folded in):
// reads edge_attr directly, writes src/ae/packed-f16 at CSR position.
__global__ __launch_bounds__(256) void k_scatter(
    const int* __restrict__ srcv, const int* __restrict__ dstv,
    const float* __restrict__ ea, const float* __restrict__ wewa1,
    const int* __restrict__ row_ptr, int* __restrict__ fill,
    int* __restrict__ csr_src, float* __restrict__ ae_csr,
    uint* __restrict__ ea16_csr)
{
    __shared__ float w[64];
    int t = threadIdx.x;
    if (t < 64) w[t] = wewa1[t];
    __syncthreads();
    int e = blockIdx.x * 256 + t;
    int d = dstv[e];
    int pos = row_ptr[d] + atomicAdd(&fill[d], 1);
    csr_src[pos] = srcv[e];
    const float4* p = (const float4*)(ea + (size_t)e * 16);
    float4 v0 = p[0], v1 = p[1], v2 = p[2], v3 = p[3];
    float eav[16] = {v0.x, v0.y, v0.z, v0.w, v1.x, v1.y, v1.z, v1.w,
                     v2.x, v2.y, v2.z, v2.w, v3.x, v3.y, v3.z, v3.w};
    float a0 = 0.f, a1 = 0.f, a2 = 0.f, a3 = 0.f;
#pragma unroll
    for (int k = 0; k < 16; k++) {
        a0 = fmaf(eav[k], w[k * 4 + 0], a0);
        a1 = fmaf(eav[k], w[k * 4 + 1], a1);
        a2 = fmaf(eav[k], w[k * 4 + 2], a2);
        a3 = fmaf(eav[k], w[k * 4 + 3], a3);
    }
    float4 r; r.x = a0; r.y = a1; r.z = a2; r.w = a3;
    *(float4*)(ae_csr + (size_t)pos * 4) = r;
    uint4 pa, pb;
    pa.x = pk16(eav[0], eav[1]);  pa.y = pk16(eav[2], eav[3]);
    pa.z = pk16(eav[4], eav[5]);  pa.w = pk16(eav[6], eav[7]);
    pb.x = pk16(eav[8], eav[9]);  pb.y = pk16(eav[10], eav[11]);
    pb.z = pk16(eav[12], eav[13]); pb.w = pk16(eav[14], eav[15]);
    uint4* d16 = (uint4*)(ea16_csr + (size_t)pos * 8);
    d16[0] = pa; d16[1] = pb;
}

// ---------------- per-timestep kernels ----------------

// Fused: xp16 = f16(xc @ Wn) head-interleaved [n*256 + lane*4 + h]
//        + aij (a_i/a_j folded projections) for the same 16-node tile.
__global__ __launch_bounds__(256) void k_xpaij(
    const float* __restrict__ xc, const float* __restrict__ Wn,
    const float* __restrict__ wnwa0, const float* __restrict__ wnwa2,
    f16* __restrict__ xp16, float* __restrict__ aijI, float* __restrict__ aijJ)
{
    __shared__ float xcs[16][64];
    int t = threadIdx.x;
    int nb = blockIdx.x * 16;
    {
        int g = t >> 4, k4 = t & 15;
        ((float4*)&xcs[g][0])[k4] = ((const float4*)(xc + (size_t)(nb + g) * 64))[k4];
    }
    __syncthreads();
    float acc[16];
#pragma unroll
    for (int g = 0; g < 16; g++) acc[g] = 0.f;
    for (int k = 0; k < 64; k += 4) {
        float w0 = Wn[k * 256 + t], w1 = Wn[(k + 1) * 256 + t];
        float w2 = Wn[(k + 2) * 256 + t], w3 = Wn[(k + 3) * 256 + t];
#pragma unroll
        for (int g = 0; g < 16; g++) {
            float4 xv = *(const float4*)&xcs[g][k];
            acc[g] = fmaf(xv.w, w3, fmaf(xv.z, w2, fmaf(xv.y, w1, fmaf(xv.x, w0, acc[g]))));
        }
    }
    int h = t >> 6, lane = t & 63;
#pragma unroll
    for (int g = 0; g < 16; g++)
        xp16[(size_t)(nb + g) * 256 + lane * 4 + h] = (f16)acc[g];
    // aij for the tile: threads 0..63, rotated k to avoid LDS bank pileup
    if (t < 64) {
        int nn = t >> 2, hh = t & 3;
        int k0 = nn * 4;
        float a_i = 0.f, a_j = 0.f;
        for (int kk = 0; kk < 64; kk++) {
            int k = (k0 + kk) & 63;
            float xv = xcs[nn][k];
            a_i = fmaf(xv, wnwa0[k * 4 + hh], a_i);
            a_j = fmaf(xv, wnwa2[k * 4 + hh], a_j);
        }
        aijI[(size_t)(nb + nn) * 4 + hh] = a_i;
        aijJ[(size_t)(nb + nn) * 4 + hh] = a_j;
    }
}

#define LEAKY(v) ((v) > 0.f ? (v) : 0.2f * (v))

// Softmax + aggregation: one wave per dst node, 4 nodes per 256-thread block.
// Softmax phase stages ea16 + weights + src ids in LDS; aggregation loop runs
// groups of 4 edges with one broadcast ds_read_b128 for src ids and 4
// independent xp gathers in flight (one group prefetched ahead).
__global__ __launch_bounds__(256) void k_node(
    const int* __restrict__ row_ptr, const int* __restrict__ csr_src,
    const float* __restrict__ ae_csr, const float* __restrict__ aijI,
    const float* __restrict__ aijJ, const f16* __restrict__ xp16,
    const uint* __restrict__ ea16_csr, const uint* __restrict__ WeP,
    float* __restrict__ aggr)
{
    __shared__ float wbuf[4][64][4];   // 4 KB
    __shared__ uint  eabuf[4][64][8];  // 8 KB
    __shared__ int   srcbuf[4][72];    // 1.1 KB (8-pad for uint4 overread)
    int t = threadIdx.x, wid = t >> 6, lane = t & 63;
    int n = blockIdx.x * 4 + wid;
    f16x2 wep[4][8];
#pragma unroll
    for (int h = 0; h < 4; h++)
#pragma unroll
        for (int jp = 0; jp < 8; jp++)
            wep[h][jp] = bc16(WeP[(h * 8 + jp) * 64 + lane]);
    int r0 = row_ptr[n], r1 = row_ptr[n + 1];
    int deg = r1 - r0;
    float acc0 = 0.f, acc1 = 0.f, acc2 = 0.f, acc3 = 0.f;
    uint loff = (uint)lane << 2;
    if (lane < 8) srcbuf[wid][64 + lane] = 0;

    auto agg_edge = [&](int j, uint2 xu) {
        float4 w4 = *(const float4*)&wbuf[wid][j][0];
        const uint4* eb = (const uint4*)&eabuf[wid][j][0];
        uint4 u0 = eb[0], u1 = eb[1];
        f16x2 e0 = bc16(u0.x), e1 = bc16(u0.y), e2 = bc16(u0.z), e3 = bc16(u0.w);
        f16x2 e4 = bc16(u1.x), e5 = bc16(u1.y), e6 = bc16(u1.z), e7 = bc16(u1.w);
        f16x2 x01 = bc16(xu.x), x23 = bc16(xu.y);
        float ep0, ep1, ep2, ep3;
        ep0 = __builtin_amdgcn_fdot2(e0, wep[0][0], 0.f, false);
        ep1 = __builtin_amdgcn_fdot2(e0, wep[1][0], 0.f, false);
        ep2 = __builtin_amdgcn_fdot2(e0, wep[2][0], 0.f, false);
        ep3 = __builtin_amdgcn_fdot2(e0, wep[3][0], 0.f, false);
        ep0 = __builtin_amdgcn_fdot2(e1, wep[0][1], ep0, false);
        ep1 = __builtin_amdgcn_fdot2(e1, wep[1][1], ep1, false);
        ep2 = __builtin_amdgcn_fdot2(e1, wep[2][1], ep2, false);
        ep3 = __builtin_amdgcn_fdot2(e1, wep[3][1], ep3, false);
        ep0 = __builtin_amdgcn_fdot2(e2, wep[0][2], ep0, false);
        ep1 = __builtin_amdgcn_fdot2(e2, wep[1][2], ep1, false);
        ep2 = __builtin_amdgcn_fdot2(e2, wep[2][2], ep2, false);
        ep3 = __builtin_amdgcn_fdot2(e2, wep[3][2], ep3, false);
        ep0 = __builtin_amdgcn_fdot2(e3, wep[0][3], ep0, false);
        ep1 = __builtin_amdgcn_fdot2(e3, wep[1][3], ep1, false);
        ep2 = __builtin_amdgcn_fdot2(e3, wep[2][3], ep2, false);
        ep3 = __builtin_amdgcn_fdot2(e3, wep[3][3], ep3, false);
        ep0 = __builtin_amdgcn_fdot2(e4, wep[0][4], ep0, false);
        ep1 = __builtin_amdgcn_fdot2(e4, wep[1][4], ep1, false);
        ep2 = __builtin_amdgcn_fdot2(e4, wep[2][4], ep2, false);
        ep3 = __builtin_amdgcn_fdot2(e4, wep[3][4], ep3, false);
        ep0 = __builtin_amdgcn_fdot2(e5, wep[0][5], ep0, false);
        ep1 = __builtin_amdgcn_fdot2(e5, wep[1][5], ep1, false);
        ep2 = __builtin_amdgcn_fdot2(e5, wep[2][5], ep2, false);
        ep3 = __builtin_amdgcn_fdot2(e5, wep[3][5], ep3, false);
        ep0 = __builtin_amdgcn_fdot2(e6, wep[0][6], ep0, false);
        ep1 = __builtin_amdgcn_fdot2(e6, wep[1][6], ep1, false);
        ep2 = __builtin_amdgcn_fdot2(e6, wep[2][6], ep2, false);
        ep3 = __builtin_amdgcn_fdot2(e6, wep[3][6], ep3, false);
        ep0 = __builtin_amdgcn_fdot2(e7, wep[0][7], ep0, false);
        ep1 = __builtin_amdgcn_fdot2(e7, wep[1][7], ep1, false);
        ep2 = __builtin_amdgcn_fdot2(e7, wep[2][7], ep2, false);
        ep3 = __builtin_amdgcn_fdot2(e7, wep[3][7], ep3, false);
        acc0 = fmaf(w4.x * ep0, (float)x01[0], acc0);
        acc1 = fmaf(w4.y * ep1, (float)x01[1], acc1);
        acc2 = fmaf(w4.z * ep2, (float)x23[0], acc2);
        acc3 = fmaf(w4.w * ep3, (float)x23[1], acc3);
    };
    auto xload = [&](uint sj) {
        return *(const uint2*)(xp16 + ((sj << 8) + loff));
    };

    if (deg > 0 && deg <= 64) {
        float4 ai = *(const float4*)(aijI + (size_t)n * 4);
        float al0 = -1e30f, al1 = -1e30f, al2 = -1e30f, al3 = -1e30f;
        int sreg = 0;
        if (lane < deg) {
            int p = r0 + lane;
            sreg = csr_src[p];
            float4 a4 = *(const float4*)(ae_csr + (size_t)p * 4);
            float4 aj = *(const float4*)(aijJ + (size_t)sreg * 4);
            const uint4* ep16 = (const uint4*)(ea16_csr + (size_t)p * 8);
            uint4 ua = ep16[0], ub = ep16[1];
            *(uint4*)&eabuf[wid][lane][0] = ua;
            *(uint4*)&eabuf[wid][lane][4] = ub;
            al0 = LEAKY(ai.x + a4.x + aj.x);
            al1 = LEAKY(ai.y + a4.y + aj.y);
            al2 = LEAKY(ai.z + a4.z + aj.z);
            al3 = LEAKY(ai.w + a4.w + aj.w);
        }
        srcbuf[wid][lane] = (lane < deg) ? sreg : 0;
        float m0 = wred_max(al0), m1 = wred_max(al1);
        float m2 = wred_max(al2), m3 = wred_max(al3);
        float p0 = (lane < deg) ? __expf(al0 - m0) : 0.f;
        float p1 = (lane < deg) ? __expf(al1 - m1) : 0.f;
        float p2 = (lane < deg) ? __expf(al2 - m2) : 0.f;
        float p3 = (lane < deg) ? __expf(al3 - m3) : 0.f;
        float s0 = wred_sum(p0), s1 = wred_sum(p1);
        float s2 = wred_sum(p2), s3 = wred_sum(p3);
        float4 w4v;
        w4v.x = p0 * (1.f / (s0 + 1e-16f));
        w4v.y = p1 * (1.f / (s1 + 1e-16f));
        w4v.z = p2 * (1.f / (s2 + 1e-16f));
        w4v.w = p3 * (1.f / (s3 + 1e-16f));
        *(float4*)&wbuf[wid][lane][0] = w4v;
        asm volatile("s_waitcnt lgkmcnt(0)" ::: "memory");
        // group-of-4 pipelined gather loop
        uint4 s4 = *(const uint4*)&srcbuf[wid][0];
        uint2 x0 = xload(s4.x), x1 = xload(s4.y), x2 = xload(s4.z), x3 = xload(s4.w);
        int j = 0;
        while (j + 4 < deg) {
            uint4 s4n = *(const uint4*)&srcbuf[wid][j + 4];
            uint2 n0 = xload(s4n.x), n1 = xload(s4n.y);
            uint2 n2 = xload(s4n.z), n3 = xload(s4n.w);
            agg_edge(j, x0); agg_edge(j + 1, x1);
            agg_edge(j + 2, x2); agg_edge(j + 3, x3);
            x0 = n0; x1 = n1; x2 = n2; x3 = n3;
            j += 4;
        }
        if (j < deg)     agg_edge(j, x0);
        if (j + 1 < deg) agg_edge(j + 1, x1);
        if (j + 2 < deg) agg_edge(j + 2, x2);
        if (j + 3 < deg) agg_edge(j + 3, x3);
    } else if (deg > 0) {
        // generic slow path (deg > 64): online softmax over 64-edge batches
        float4 ai = *(const float4*)(aijI + (size_t)n * 4);
        float m0 = -1e30f, m1 = -1e30f, m2 = -1e30f, m3 = -1e30f;
        float s0 = 0.f, s1 = 0.f, s2 = 0.f, s3 = 0.f;
        for (int base = r0; base < r1; base += 64) {
            int p = base + lane;
            if (p < r1) {
                int s = csr_src[p];
                float4 a4 = *(const float4*)(ae_csr + (size_t)p * 4);
                float4 aj = *(const float4*)(aijJ + (size_t)s * 4);
                float al0 = LEAKY(ai.x + a4.x + aj.x);
                float al1 = LEAKY(ai.y + a4.y + aj.y);
                float al2 = LEAKY(ai.z + a4.z + aj.z);
                float al3 = LEAKY(ai.w + a4.w + aj.w);
                float nm;
                nm = fmaxf(m0, al0); s0 = s0 * __expf(m0 - nm) + __expf(al0 - nm); m0 = nm;
                nm = fmaxf(m1, al1); s1 = s1 * __expf(m1 - nm) + __expf(al1 - nm); m1 = nm;
                nm = fmaxf(m2, al2); s2 = s2 * __expf(m2 - nm) + __expf(al2 - nm); m2 = nm;
                nm = fmaxf(m3, al3); s3 = s3 * __expf(m3 - nm) + __expf(al3 - nm); m3 = nm;
            }
        }
#pragma unroll
        for (int off = 32; off; off >>= 1) {
            float om, os, nm;
            om = __shfl_xor(m0, off, 64); os = __shfl_xor(s0, off, 64);
            nm = fmaxf(m0, om); s0 = s0 * __expf(m0 - nm) + os * __expf(om - nm); m0 = nm;
            om = __shfl_xor(m1, off, 64); os = __shfl_xor(s1, off, 64);
            nm = fmaxf(m1, om); s1 = s1 * __expf(m1 - nm) + os * __expf(om - nm); m1 = nm;
            om = __shfl_xor(m2, off, 64); os = __shfl_xor(s2, off, 64);
            nm = fmaxf(m2, om); s2 = s2 * __expf(m2 - nm) + os * __expf(om - nm); m2 = nm;
            om = __shfl_xor(m3, off, 64); os = __shfl_xor(s3, off, 64);
            nm = fmaxf(m3, om); s3 = s3 * __expf(m3 - nm) + os * __expf(om - nm); m3 = nm;
        }
        float rd0 = 1.f / (s0 + 1e-16f), rd1 = 1.f / (s1 + 1e-16f);
        float rd2 = 1.f / (s2 + 1e-16f), rd3 = 1.f / (s3 + 1e-16f);
        for (int base = r0; base < r1; base += 64) {
            int cnt = min(64, r1 - base);
            int sreg = 0;
            if (lane < cnt) {
                int p = base + lane;
                sreg = csr_src[p];
                float4 a4 = *(const float4*)(ae_csr + (size_t)p * 4);
                float4 aj = *(const float4*)(aijJ + (size_t)sreg * 4);
                const uint4* ep16 = (const uint4*)(ea16_csr + (size_t)p * 8);
                uint4 ua = ep16[0], ub = ep16[1];
                *(uint4*)&eabuf[wid][lane][0] = ua;
                *(uint4*)&eabuf[wid][lane][4] = ub;
                float al0 = LEAKY(ai.x + a4.x + aj.x);
                float al1 = LEAKY(ai.y + a4.y + aj.y);
                float al2 = LEAKY(ai.z + a4.z + aj.z);
                float al3 = LEAKY(ai.w + a4.w + aj.w);
                float4 w4v;
                w4v.x = __expf(al0 - m0) * rd0;
                w4v.y = __expf(al1 - m1) * rd1;
                w4v.z = __expf(al2 - m2) * rd2;
                w4v.w = __expf(al3 - m3) * rd3;
                *(float4*)&wbuf[wid][lane][0] = w4v;
            }
            srcbuf[wid][lane] = (lane < cnt) ? sreg : 0;
            asm volatile("s_waitcnt lgkmcnt(0)" ::: "memory");
            for (int j = 0; j < cnt; j++) {
                uint sj = (uint)srcbuf[wid][j];
                agg_edge(j, xload(sj));
            }
            asm volatile("s_waitcnt lgkmcnt(0)" ::: "memory");
        }
    }
    float* ag = aggr + (size_t)n * 256 + lane;
    ag[0] = acc0; ag[64] = acc1; ag[128] = acc2; ag[192] = acc3;
}

// aggr@Ws + b -> celu -> GRU -> LayerNorm ; 32 nodes per 256-thread block
#define PNB 32
__global__ __launch_bounds__(256) void k_post(
    const float* __restrict__ aggr, const float* __restrict__ Ws,
    const float* __restrict__ bvec, const float* __restrict__ h_in,
    float* __restrict__ h_out, const float* __restrict__ wihT,
    const float* __restrict__ whhT, const float* __restrict__ bih,
    const float* __restrict__ bhh, const float* __restrict__ gamma,
    const float* __restrict__ beta, float* __restrict__ xc_out)
{
    __shared__ float agg[PNB][256];   // 32 KB
    __shared__ float mld[PNB][64];    // 8 KB
    __shared__ float hld[PNB][64];    // 8 KB
    int t = threadIdx.x;
    int lane = t & 63, g = t >> 6;
    int nb = blockIdx.x * PNB;
    int nrem = NNODES - nb; if (nrem > PNB) nrem = PNB;

    for (int i = t; i < nrem * 64; i += 256)
        ((float4*)agg)[i] = ((const float4*)(aggr + (size_t)nb * 256))[i];
    for (int i = t; i < nrem * 16; i += 256)
        ((float4*)hld)[i] = ((const float4*)(h_in + (size_t)nb * 64))[i];
    __syncthreads();

    int n0 = g * 8;
    float bj = bvec[lane];
    float acc[8];
#pragma unroll
    for (int u = 0; u < 8; u++) acc[u] = bj;
    for (int q = 0; q < 256; q += 4) {
        float w0 = Ws[q * 64 + lane];
        float w1 = Ws[(q + 1) * 64 + lane];
        float w2 = Ws[(q + 2) * 64 + lane];
        float w3 = Ws[(q + 3) * 64 + lane];
#pragma unroll
        for (int u = 0; u < 8; u++) {
            float4 a = *(const float4*)&agg[n0 + u][q];
            acc[u] = fmaf(a.w, w3, fmaf(a.z, w2, fmaf(a.y, w1, fmaf(a.x, w0, acc[u]))));
        }
    }
#pragma unroll
    for (int u = 0; u < 8; u++)
        mld[n0 + u][lane] = acc[u] > 0.f ? acc[u] : expm1f(acc[u]);
    __syncthreads();

    float gi0[8], gi1[8], gi2[8], gh0[8], gh1[8], gh2[8];
    float bi0 = bih[lane], bi1 = bih[64 + lane], bi2 = bih[128 + lane];
    float bh0 = bhh[lane], bh1 = bhh[64 + lane], bh2 = bhh[128 + lane];
#pragma unroll
    for (int u = 0; u < 8; u++) {
        gi0[u] = bi0; gi1[u] = bi1; gi2[u] = bi2;
        gh0[u] = bh0; gh1[u] = bh1; gh2[u] = bh2;
    }
    for (int k = 0; k < 64; k++) {
        const float* wi = wihT + k * 192;
        const float* wh = whhT + k * 192;
        float wi0 = wi[lane], wi1 = wi[64 + lane], wi2 = wi[128 + lane];
        float wh0 = wh[lane], wh1 = wh[64 + lane], wh2 = wh[128 + lane];
#pragma unroll
        for (int u = 0; u < 8; u++) {
            float mk = mld[n0 + u][k], hk = hld[n0 + u][k];
            gi0[u] = fmaf(mk, wi0, gi0[u]);
            gi1[u] = fmaf(mk, wi1, gi1[u]);
            gi2[u] = fmaf(mk, wi2, gi2[u]);
            gh0[u] = fmaf(hk, wh0, gh0[u]);
            gh1[u] = fmaf(hk, wh1, gh1[u]);
            gh2[u] = fmaf(hk, wh2, gh2[u]);
        }
    }
    float gj = gamma[lane], btj = beta[lane];
#pragma unroll
    for (int u = 0; u < 8; u++) {
        float hv = hld[n0 + u][lane];
        float r = 1.f / (1.f + expf(-(gi0[u] + gh0[u])));
        float z = 1.f / (1.f + expf(-(gi1[u] + gh1[u])));
        float nv = tanhf(gi2[u] + r * gh2[u]);
        float hnew = (1.f - z) * nv + z * hv;
        float sum = hnew, sq = hnew * hnew;
#pragma unroll
        for (int off = 32; off; off >>= 1) {
            sum += __shfl_xor(sum, off, 64);
            sq += __shfl_xor(sq, off, 64);
        }
        float mu = sum * (1.f / 64.f);
        float var = sq * (1.f / 64.f) - mu * mu;
        float xcv = (hnew - mu) * rsqrtf(var + 1e-5f) * gj + btj;
        if (n0 + u < nrem) {
            h_out[(size_t)(nb + n0 + u) * 64 + lane] = hnew;
            xc_out[(size_t)(nb + n0 + u) * 64 + lane] = xcv;
        }
    }
}

// ---------------- launcher ----------------

extern "C" void kernel_launch(void* const* d_in, const int* in_sizes, int n_in,
                              void* d_out, int out_size, void* d_ws, size_t ws_size,
                              hipStream_t stream)
{
    const float* x         = (const float*)d_in[0];
    const int*   edge_index= (const int*)d_in[1];
    const float* edge_attr = (const float*)d_in[2];
    const float* Wn        = (const float*)d_in[3];
    const float* We        = (const float*)d_in[4];
    const float* Wa        = (const float*)d_in[5];
    const float* Ws        = (const float*)d_in[6];
    const float* bv        = (const float*)d_in[7];
    const float* Wih       = (const float*)d_in[8];
    const float* Whh       = (const float*)d_in[9];
    const float* bih       = (const float*)d_in[10];
    const float* bhh       = (const float*)d_in[11];
    const float* gamma     = (const float*)d_in[12];
    const float* beta      = (const float*)d_in[13];
    float* out = (float*)d_out;

    const int* src = edge_index;
    const int* dst = edge_index + NEDGES;

    char* w = (char*)d_ws;
    auto alloc = [&](size_t bytes) {
        char* p = w;
        w += (bytes + 255) & ~(size_t)255;
        return p;
    };
    f16*   xp16     = (f16*)alloc((size_t)NNODES * 256 * 2);
    float* aggr     = (float*)alloc((size_t)NNODES * 256 * 4);
    float* ae_csr   = (float*)alloc((size_t)NEDGES * 4 * 4);
    uint*  ea16_csr = (uint*)alloc((size_t)NEDGES * 8 * 4);
    float* hbuf     = (float*)alloc((size_t)NNODES * 64 * 4);
    float* aijI     = (float*)alloc((size_t)NNODES * 4 * 4);
    float* aijJ     = (float*)alloc((size_t)NNODES * 4 * 4);
    int*   counts   = (int*)alloc((size_t)NNODES * 4);
    int*   fill     = (int*)alloc((size_t)NNODES * 4);
    int*   row_ptr  = (int*)alloc((size_t)(NNODES + 1) * 4);
    int*   csr_src  = (int*)alloc((size_t)NEDGES * 4);
    float* wnwa0    = (float*)alloc(256 * 4);
    float* wnwa2    = (float*)alloc(256 * 4);
    float* wewa1    = (float*)alloc(64 * 4);
    float* wihT     = (float*)alloc(192 * 64 * 4);
    float* whhT     = (float*)alloc(192 * 64 * 4);
    uint*  WeP      = (uint*)alloc(2048 * 4);

    k_fold<<<1, 256, 0, stream>>>(Wn, We, Wa, Wih, Whh, wnwa0, wnwa2, wewa1,
                                  wihT, whhT, WeP);
    hipMemsetAsync(counts, 0, (size_t)NNODES * 4, stream);
    hipMemsetAsync(fill, 0, (size_t)NNODES * 4, stream);
    k_hist<<<NEDGES / 256, 256, 0, stream>>>(dst, counts);
    k_scan<<<1, 1024, 0, stream>>>(counts, row_ptr, NNODES);
    k_scatter<<<NEDGES / 256, 256, 0, stream>>>(src, dst, edge_attr, wewa1,
                                                row_ptr, fill, csr_src,
                                                ae_csr, ea16_csr);

    for (int step = 0; step < 3; step++) {
        const float* xc_in = (step == 0) ? x : out;
        const float* h_in  = (step == 0) ? x : hbuf;
        k_xpaij<<<NNODES / 16, 256, 0, stream>>>(xc_in, Wn, wnwa0, wnwa2,
                                                 xp16, aijI, aijJ);
        k_node<<<NNODES / 4, 256, 0, stream>>>(row_ptr, csr_src, ae_csr, aijI,
                                               aijJ, xp16, ea16_csr, WeP, aggr);
        k_post<<<(NNODES + PNB - 1) / PNB, 256, 0, stream>>>(
            aggr, Ws, bv, h_in, hbuf, wihT, whhT, bih, bhh, gamma, beta, out);
    }
}

// Round 6
// 675.194 us; speedup vs baseline: 2.3035x; 1.3460x over previous
//
#include <hip/hip_runtime.h>
#include <math.h>

#define NNODES 50000
#define NEDGES 800000
// DIM=64, EDGE_DIM=16, HEADS=4, HC=256

typedef _Float16 f16;
typedef _Float16 f16x2 __attribute__((ext_vector_type(2)));
typedef _Float16 f16x8 __attribute__((ext_vector_type(8)));
typedef float f32x4 __attribute__((ext_vector_type(4)));

__device__ inline uint pk16(float a, float b) {
    union { f16x2 h; uint u; } c;
    c.h[0] = (f16)a; c.h[1] = (f16)b;
    return c.u;
}
__device__ inline f16x2 bc16(uint u) {
    union { uint u; f16x2 h; } c; c.u = u; return c.h;
}
__device__ inline float wred_max(float v) {
#pragma unroll
    for (int off = 32; off; off >>= 1) v = fmaxf(v, __shfl_xor(v, off, 64));
    return v;
}
__device__ inline float wred_sum(float v) {
#pragma unroll
    for (int off = 32; off; off >>= 1) v += __shfl_xor(v, off, 64);
    return v;
}

// ---------------- one-time prep kernels ----------------

// Fold Wa into Wn/We; pack We + Ws + Wih + Whh into f16 MFMA fragment layouts.
// Fragment convention (16x16x32): lane l, elem j covers k = (l>>4)*8 + j
// (any consistent A/B k-permutation is valid); B-frag entry = B[k][16t+(l&15)].
__global__ __launch_bounds__(256) void k_fold(
    const float* __restrict__ Wn, const float* __restrict__ We,
    const float* __restrict__ Wa, const float* __restrict__ Wih,
    const float* __restrict__ Whh, const float* __restrict__ Ws,
    float* __restrict__ wnwa0, float* __restrict__ wnwa2,
    float* __restrict__ wewa1, uint* __restrict__ WeP,
    f16* __restrict__ WsP, f16* __restrict__ WihP, f16* __restrict__ WhhP)
{
    int t = threadIdx.x;
    {
        int k = t >> 2, h = t & 3;
        float s0 = 0.f, s2 = 0.f;
        for (int c = 0; c < 64; c++) {
            float wn = Wn[k * 256 + h * 64 + c];
            s0 = fmaf(wn, Wa[h * 192 + c], s0);
            s2 = fmaf(wn, Wa[h * 192 + 128 + c], s2);
        }
        wnwa0[t] = s0;
        wnwa2[t] = s2;
    }
    if (t < 64) {
        int k = t >> 2, h = t & 3;
        float s1 = 0.f;
        for (int c = 0; c < 64; c++)
            s1 = fmaf(We[k * 256 + h * 64 + c], Wa[h * 192 + 64 + c], s1);
        wewa1[t] = s1;
    }
    // WeP[(h*8+jp)*64 + lane] = pack(We[2jp][h*64+lane], We[2jp+1][h*64+lane])
    for (int idx = t; idx < 2048; idx += 256) {
        int h = idx >> 9, rem = idx & 511;
        int jp = rem >> 6, lane = rem & 63;
        int c = h * 64 + lane, k0 = 2 * jp;
        WeP[idx] = pk16(We[k0 * 256 + c], We[(k0 + 1) * 256 + c]);
    }
    // WsP: e = (ks*4+tt)*64 + l  (ks=0..7, tt=0..3), entry j = Ws[k][16tt+ll]
    for (int e = t; e < 2048; e += 256) {
        int l = e & 63, tt = (e >> 6) & 3, ks = e >> 8;
        int lg = l >> 4, ll = l & 15;
        f16* o = WsP + (size_t)e * 8;
        for (int j = 0; j < 8; j++)
            o[j] = (f16)Ws[(ks * 32 + lg * 8 + j) * 64 + tt * 16 + ll];
    }
    // WihP/WhhP: e = (ks*12+tt)*64 + l (ks=0..1, tt=0..11),
    // entry j = W[16tt+ll][ks*32+lg*8+j]  (B[k][out] = W[out][k])
    for (int e = t; e < 1536; e += 256) {
        int l = e & 63, q = e >> 6;
        int tt = q % 12, ks = q / 12;
        int lg = l >> 4, ll = l & 15;
        int outc = tt * 16 + ll;
        for (int j = 0; j < 8; j++) {
            int k = ks * 32 + lg * 8 + j;
            WihP[(size_t)e * 8 + j] = (f16)Wih[outc * 64 + k];
            WhhP[(size_t)e * 8 + j] = (f16)Whh[outc * 64 + k];
        }
    }
}

__global__ __launch_bounds__(256) void k_hist(const int* __restrict__ dst, int* __restrict__ counts)
{
    int e = blockIdx.x * 256 + threadIdx.x;
    atomicAdd(&counts[dst[e]], 1);
}

// shfl-based scan: 2 syncthreads per 1024-chunk
__global__ __launch_bounds__(1024) void k_scan(const int* __restrict__ counts,
                                               int* __restrict__ row_ptr, int n)
{
    __shared__ int wsum[16];
    int t = threadIdx.x, wid = t >> 6, lane = t & 63;
    int running = 0;
    for (int base = 0; base < n; base += 1024) {
        int idx = base + t;
        int c = (idx < n) ? counts[idx] : 0;
        int v = c;
#pragma unroll
        for (int off = 1; off < 64; off <<= 1) {
            int u = __shfl_up(v, off, 64);
            if (lane >= off) v += u;
        }
        if (lane == 63) wsum[wid] = v;
        __syncthreads();
        int wpre = 0, tot = 0;
#pragma unroll
        for (int wk = 0; wk < 16; wk++) {
            int s = wsum[wk];
            if (wk < wid) wpre += s;
            tot += s;
        }
        if (idx < n) row_ptr[idx] = running + wpre + v - c;  // exclusive
        running += tot;
        __syncthreads();
    }
    if (t == 0) row_ptr[n] = running;
}

// Build CSR with fused ae compute + f16 pack.
__global__ __launch_bounds__(256) void k_scatter(
    const int* __restrict__ srcv, const int* __restrict__ dstv,
    const float* __restrict__ ea, const float* __restrict__ wewa1,
    const int* __restrict__ row_ptr, int* __restrict__ fill,
    int* __restrict__ csr_src, float* __restrict__ ae_csr,
    uint* __restrict__ ea16_csr)
{
    __shared__ float w[64];
    int t = threadIdx.x;
    if (t < 64) w[t] = wewa1[t];
    __syncthreads();
    int e = blockIdx.x * 256 + t;
    int d = dstv[e];
    int pos = row_ptr[d] + atomicAdd(&fill[d], 1);
    csr_src[pos] = srcv[e];
    const float4* p = (const float4*)(ea + (size_t)e * 16);
    float4 v0 = p[0], v1 = p[1], v2 = p[2], v3 = p[3];
    float eav[16] = {v0.x, v0.y, v0.z, v0.w, v1.x, v1.y, v1.z, v1.w,
                     v2.x, v2.y, v2.z, v2.w, v3.x, v3.y, v3.z, v3.w};
    float a0 = 0.f, a1 = 0.f, a2 = 0.f, a3 = 0.f;
#pragma unroll
    for (int k = 0; k < 16; k++) {
        a0 = fmaf(eav[k], w[k * 4 + 0], a0);
        a1 = fmaf(eav[k], w[k * 4 + 1], a1);
        a2 = fmaf(eav[k], w[k * 4 + 2], a2);
        a3 = fmaf(eav[k], w[k * 4 + 3], a3);
    }
    float4 r; r.x = a0; r.y = a1; r.z = a2; r.w = a3;
    *(float4*)(ae_csr + (size_t)pos * 4) = r;
    uint4 pa, pb;
    pa.x = pk16(eav[0], eav[1]);  pa.y = pk16(eav[2], eav[3]);
    pa.z = pk16(eav[4], eav[5]);  pa.w = pk16(eav[6], eav[7]);
    pb.x = pk16(eav[8], eav[9]);  pb.y = pk16(eav[10], eav[11]);
    pb.z = pk16(eav[12], eav[13]); pb.w = pk16(eav[14], eav[15]);
    uint4* d16 = (uint4*)(ea16_csr + (size_t)pos * 8);
    d16[0] = pa; d16[1] = pb;
}

// ---------------- per-timestep kernels ----------------

// Fused: xp16 = f16(xc @ Wn) head-interleaved [n*256 + lane*4 + h] + aij.
__global__ __launch_bounds__(256) void k_xpaij(
    const float* __restrict__ xc, const float* __restrict__ Wn,
    const float* __restrict__ wnwa0, const float* __restrict__ wnwa2,
    f16* __restrict__ xp16, float* __restrict__ aijI, float* __restrict__ aijJ)
{
    __shared__ float xcs[16][64];
    int t = threadIdx.x;
    int nb = blockIdx.x * 16;
    {
        int g = t >> 4, k4 = t & 15;
        ((float4*)&xcs[g][0])[k4] = ((const float4*)(xc + (size_t)(nb + g) * 64))[k4];
    }
    __syncthreads();
    float acc[16];
#pragma unroll
    for (int g = 0; g < 16; g++) acc[g] = 0.f;
    for (int k = 0; k < 64; k += 4) {
        float w0 = Wn[k * 256 + t], w1 = Wn[(k + 1) * 256 + t];
        float w2 = Wn[(k + 2) * 256 + t], w3 = Wn[(k + 3) * 256 + t];
#pragma unroll
        for (int g = 0; g < 16; g++) {
            float4 xv = *(const float4*)&xcs[g][k];
            acc[g] = fmaf(xv.w, w3, fmaf(xv.z, w2, fmaf(xv.y, w1, fmaf(xv.x, w0, acc[g]))));
        }
    }
    int h = t >> 6, lane = t & 63;
#pragma unroll
    for (int g = 0; g < 16; g++)
        xp16[(size_t)(nb + g) * 256 + lane * 4 + h] = (f16)acc[g];
    if (t < 64) {
        int nn = t >> 2, hh = t & 3;
        int k0 = nn * 4;
        float a_i = 0.f, a_j = 0.f;
        for (int kk = 0; kk < 64; kk++) {
            int k = (k0 + kk) & 63;
            float xv = xcs[nn][k];
            a_i = fmaf(xv, wnwa0[k * 4 + hh], a_i);
            a_j = fmaf(xv, wnwa2[k * 4 + hh], a_j);
        }
        aijI[(size_t)(nb + nn) * 4 + hh] = a_i;
        aijJ[(size_t)(nb + nn) * 4 + hh] = a_j;
    }
}

#define LEAKY(v) ((v) > 0.f ? (v) : 0.2f * (v))

// Softmax + aggregation: one wave per dst node, 4 nodes per 256-thread block.
// Outputs aggr16 (f16, [n][h*64+c]).
__global__ __launch_bounds__(256) void k_node(
    const int* __restrict__ row_ptr, const int* __restrict__ csr_src,
    const float* __restrict__ ae_csr, const float* __restrict__ aijI,
    const float* __restrict__ aijJ, const f16* __restrict__ xp16,
    const uint* __restrict__ ea16_csr, const uint* __restrict__ WeP,
    f16* __restrict__ aggr16)
{
    __shared__ float wbuf[4][64][4];   // 4 KB
    __shared__ uint  eabuf[4][64][8];  // 8 KB
    __shared__ int   srcbuf[4][72];    // 1.1 KB (8-pad for uint4 overread)
    int t = threadIdx.x, wid = t >> 6, lane = t & 63;
    int n = blockIdx.x * 4 + wid;
    f16x2 wep[4][8];
#pragma unroll
    for (int h = 0; h < 4; h++)
#pragma unroll
        for (int jp = 0; jp < 8; jp++)
            wep[h][jp] = bc16(WeP[(h * 8 + jp) * 64 + lane]);
    int r0 = row_ptr[n], r1 = row_ptr[n + 1];
    int deg = r1 - r0;
    float acc0 = 0.f, acc1 = 0.f, acc2 = 0.f, acc3 = 0.f;
    uint loff = (uint)lane << 2;
    if (lane < 8) srcbuf[wid][64 + lane] = 0;

    auto agg_edge = [&](int j, uint2 xu) {
        float4 w4 = *(const float4*)&wbuf[wid][j][0];
        const uint4* eb = (const uint4*)&eabuf[wid][j][0];
        uint4 u0 = eb[0], u1 = eb[1];
        f16x2 e0 = bc16(u0.x), e1 = bc16(u0.y), e2 = bc16(u0.z), e3 = bc16(u0.w);
        f16x2 e4 = bc16(u1.x), e5 = bc16(u1.y), e6 = bc16(u1.z), e7 = bc16(u1.w);
        f16x2 x01 = bc16(xu.x), x23 = bc16(xu.y);
        float ep0, ep1, ep2, ep3;
        ep0 = __builtin_amdgcn_fdot2(e0, wep[0][0], 0.f, false);
        ep1 = __builtin_amdgcn_fdot2(e0, wep[1][0], 0.f, false);
        ep2 = __builtin_amdgcn_fdot2(e0, wep[2][0], 0.f, false);
        ep3 = __builtin_amdgcn_fdot2(e0, wep[3][0], 0.f, false);
        ep0 = __builtin_amdgcn_fdot2(e1, wep[0][1], ep0, false);
        ep1 = __builtin_amdgcn_fdot2(e1, wep[1][1], ep1, false);
        ep2 = __builtin_amdgcn_fdot2(e1, wep[2][1], ep2, false);
        ep3 = __builtin_amdgcn_fdot2(e1, wep[3][1], ep3, false);
        ep0 = __builtin_amdgcn_fdot2(e2, wep[0][2], ep0, false);
        ep1 = __builtin_amdgcn_fdot2(e2, wep[1][2], ep1, false);
        ep2 = __builtin_amdgcn_fdot2(e2, wep[2][2], ep2, false);
        ep3 = __builtin_amdgcn_fdot2(e2, wep[3][2], ep3, false);
        ep0 = __builtin_amdgcn_fdot2(e3, wep[0][3], ep0, false);
        ep1 = __builtin_amdgcn_fdot2(e3, wep[1][3], ep1, false);
        ep2 = __builtin_amdgcn_fdot2(e3, wep[2][3], ep2, false);
        ep3 = __builtin_amdgcn_fdot2(e3, wep[3][3], ep3, false);
        ep0 = __builtin_amdgcn_fdot2(e4, wep[0][4], ep0, false);
        ep1 = __builtin_amdgcn_fdot2(e4, wep[1][4], ep1, false);
        ep2 = __builtin_amdgcn_fdot2(e4, wep[2][4], ep2, false);
        ep3 = __builtin_amdgcn_fdot2(e4, wep[3][4], ep3, false);
        ep0 = __builtin_amdgcn_fdot2(e5, wep[0][5], ep0, false);
        ep1 = __builtin_amdgcn_fdot2(e5, wep[1][5], ep1, false);
        ep2 = __builtin_amdgcn_fdot2(e5, wep[2][5], ep2, false);
        ep3 = __builtin_amdgcn_fdot2(e5, wep[3][5], ep3, false);
        ep0 = __builtin_amdgcn_fdot2(e6, wep[0][6], ep0, false);
        ep1 = __builtin_amdgcn_fdot2(e6, wep[1][6], ep1, false);
        ep2 = __builtin_amdgcn_fdot2(e6, wep[2][6], ep2, false);
        ep3 = __builtin_amdgcn_fdot2(e6, wep[3][6], ep3, false);
        ep0 = __builtin_amdgcn_fdot2(e7, wep[0][7], ep0, false);
        ep1 = __builtin_amdgcn_fdot2(e7, wep[1][7], ep1, false);
        ep2 = __builtin_amdgcn_fdot2(e7, wep[2][7], ep2, false);
        ep3 = __builtin_amdgcn_fdot2(e7, wep[3][7], ep3, false);
        acc0 = fmaf(w4.x * ep0, (float)x01[0], acc0);
        acc1 = fmaf(w4.y * ep1, (float)x01[1], acc1);
        acc2 = fmaf(w4.z * ep2, (float)x23[0], acc2);
        acc3 = fmaf(w4.w * ep3, (float)x23[1], acc3);
    };
    auto xload = [&](uint sj) {
        return *(const uint2*)(xp16 + ((sj << 8) + loff));
    };

    if (deg > 0 && deg <= 64) {
        float4 ai = *(const float4*)(aijI + (size_t)n * 4);
        float al0 = -1e30f, al1 = -1e30f, al2 = -1e30f, al3 = -1e30f;
        int sreg = 0;
        if (lane < deg) {
            int p = r0 + lane;
            sreg = csr_src[p];
            float4 a4 = *(const float4*)(ae_csr + (size_t)p * 4);
            float4 aj = *(const float4*)(aijJ + (size_t)sreg * 4);
            const uint4* ep16 = (const uint4*)(ea16_csr + (size_t)p * 8);
            uint4 ua = ep16[0], ub = ep16[1];
            *(uint4*)&eabuf[wid][lane][0] = ua;
            *(uint4*)&eabuf[wid][lane][4] = ub;
            al0 = LEAKY(ai.x + a4.x + aj.x);
            al1 = LEAKY(ai.y + a4.y + aj.y);
            al2 = LEAKY(ai.z + a4.z + aj.z);
            al3 = LEAKY(ai.w + a4.w + aj.w);
        }
        srcbuf[wid][lane] = (lane < deg) ? sreg : 0;
        float m0 = wred_max(al0), m1 = wred_max(al1);
        float m2 = wred_max(al2), m3 = wred_max(al3);
        float p0 = (lane < deg) ? __expf(al0 - m0) : 0.f;
        float p1 = (lane < deg) ? __expf(al1 - m1) : 0.f;
        float p2 = (lane < deg) ? __expf(al2 - m2) : 0.f;
        float p3 = (lane < deg) ? __expf(al3 - m3) : 0.f;
        float s0 = wred_sum(p0), s1 = wred_sum(p1);
        float s2 = wred_sum(p2), s3 = wred_sum(p3);
        float4 w4v;
        w4v.x = p0 * (1.f / (s0 + 1e-16f));
        w4v.y = p1 * (1.f / (s1 + 1e-16f));
        w4v.z = p2 * (1.f / (s2 + 1e-16f));
        w4v.w = p3 * (1.f / (s3 + 1e-16f));
        *(float4*)&wbuf[wid][lane][0] = w4v;
        asm volatile("s_waitcnt lgkmcnt(0)" ::: "memory");
        uint4 s4 = *(const uint4*)&srcbuf[wid][0];
        uint2 x0 = xload(s4.x), x1 = xload(s4.y), x2 = xload(s4.z), x3 = xload(s4.w);
        int j = 0;
        while (j + 4 < deg) {
            uint4 s4n = *(const uint4*)&srcbuf[wid][j + 4];
            uint2 n0 = xload(s4n.x), n1 = xload(s4n.y);
            uint2 n2 = xload(s4n.z), n3 = xload(s4n.w);
            agg_edge(j, x0); agg_edge(j + 1, x1);
            agg_edge(j + 2, x2); agg_edge(j + 3, x3);
            x0 = n0; x1 = n1; x2 = n2; x3 = n3;
            j += 4;
        }
        if (j < deg)     agg_edge(j, x0);
        if (j + 1 < deg) agg_edge(j + 1, x1);
        if (j + 2 < deg) agg_edge(j + 2, x2);
        if (j + 3 < deg) agg_edge(j + 3, x3);
    } else if (deg > 0) {
        float4 ai = *(const float4*)(aijI + (size_t)n * 4);
        float m0 = -1e30f, m1 = -1e30f, m2 = -1e30f, m3 = -1e30f;
        float s0 = 0.f, s1 = 0.f, s2 = 0.f, s3 = 0.f;
        for (int base = r0; base < r1; base += 64) {
            int p = base + lane;
            if (p < r1) {
                int s = csr_src[p];
                float4 a4 = *(const float4*)(ae_csr + (size_t)p * 4);
                float4 aj = *(const float4*)(aijJ + (size_t)s * 4);
                float al0 = LEAKY(ai.x + a4.x + aj.x);
                float al1 = LEAKY(ai.y + a4.y + aj.y);
                float al2 = LEAKY(ai.z + a4.z + aj.z);
                float al3 = LEAKY(ai.w + a4.w + aj.w);
                float nm;
                nm = fmaxf(m0, al0); s0 = s0 * __expf(m0 - nm) + __expf(al0 - nm); m0 = nm;
                nm = fmaxf(m1, al1); s1 = s1 * __expf(m1 - nm) + __expf(al1 - nm); m1 = nm;
                nm = fmaxf(m2, al2); s2 = s2 * __expf(m2 - nm) + __expf(al2 - nm); m2 = nm;
                nm = fmaxf(m3, al3); s3 = s3 * __expf(m3 - nm) + __expf(al3 - nm); m3 = nm;
            }
        }
#pragma unroll
        for (int off = 32; off; off >>= 1) {
            float om, os, nm;
            om = __shfl_xor(m0, off, 64); os = __shfl_xor(s0, off, 64);
            nm = fmaxf(m0, om); s0 = s0 * __expf(m0 - nm) + os * __expf(om - nm); m0 = nm;
            om = __shfl_xor(m1, off, 64); os = __shfl_xor(s1, off, 64);
            nm = fmaxf(m1, om); s1 = s1 * __expf(m1 - nm) + os * __expf(om - nm); m1 = nm;
            om = __shfl_xor(m2, off, 64); os = __shfl_xor(s2, off, 64);
            nm = fmaxf(m2, om); s2 = s2 * __expf(m2 - nm) + os * __expf(om - nm); m2 = nm;
            om = __shfl_xor(m3, off, 64); os = __shfl_xor(s3, off, 64);
            nm = fmaxf(m3, om); s3 = s3 * __expf(m3 - nm) + os * __expf(om - nm); m3 = nm;
        }
        float rd0 = 1.f / (s0 + 1e-16f), rd1 = 1.f / (s1 + 1e-16f);
        float rd2 = 1.f / (s2 + 1e-16f), rd3 = 1.f / (s3 + 1e-16f);
        for (int base = r0; base < r1; base += 64) {
            int cnt = min(64, r1 - base);
            int sreg = 0;
            if (lane < cnt) {
                int p = base + lane;
                sreg = csr_src[p];
                float4 a4 = *(const float4*)(ae_csr + (size_t)p * 4);
                float4 aj = *(const float4*)(aijJ + (size_t)sreg * 4);
                const uint4* ep16 = (const uint4*)(ea16_csr + (size_t)p * 8);
                uint4 ua = ep16[0], ub = ep16[1];
                *(uint4*)&eabuf[wid][lane][0] = ua;
                *(uint4*)&eabuf[wid][lane][4] = ub;
                float al0 = LEAKY(ai.x + a4.x + aj.x);
                float al1 = LEAKY(ai.y + a4.y + aj.y);
                float al2 = LEAKY(ai.z + a4.z + aj.z);
                float al3 = LEAKY(ai.w + a4.w + aj.w);
                float4 w4v;
                w4v.x = __expf(al0 - m0) * rd0;
                w4v.y = __expf(al1 - m1) * rd1;
                w4v.z = __expf(al2 - m2) * rd2;
                w4v.w = __expf(al3 - m3) * rd3;
                *(float4*)&wbuf[wid][lane][0] = w4v;
            }
            srcbuf[wid][lane] = (lane < cnt) ? sreg : 0;
            asm volatile("s_waitcnt lgkmcnt(0)" ::: "memory");
            for (int j = 0; j < cnt; j++) {
                uint sj = (uint)srcbuf[wid][j];
                agg_edge(j, xload(sj));
            }
            asm volatile("s_waitcnt lgkmcnt(0)" ::: "memory");
        }
    }
    f16* ag = aggr16 + (size_t)n * 256 + lane;
    ag[0] = (f16)acc0; ag[64] = (f16)acc1; ag[128] = (f16)acc2; ag[192] = (f16)acc3;
}

// MFMA k_post: celu(aggr16@WsP+b) -> GRU (2x MFMA GEMM) -> LayerNorm.
// 4 waves/block, 16 nodes/wave (64 nodes/block). C-layout: col=l&15,
// row=(l>>4)*4+reg (HW-verified); k-permutation consistent across A/B frags.
__global__ __launch_bounds__(256) void k_post(
    const f16* __restrict__ aggr16, const f16* __restrict__ WsP,
    const float* __restrict__ bvec, const float* __restrict__ h_in,
    float* __restrict__ h_out, const f16* __restrict__ WihP,
    const f16* __restrict__ WhhP, const float* __restrict__ bih,
    const float* __restrict__ bhh, const float* __restrict__ gamma,
    const float* __restrict__ beta, float* __restrict__ xc_out)
{
    __shared__ __align__(16) f16 m_lds[4][16][72];  // 18 KB, +8 pad
    int t = threadIdx.x, w = t >> 6, l = t & 63;
    int lg = l >> 4, ll = l & 15;
    int nb = blockIdx.x * 64 + w * 16;
    int nodeA = nb + ll;
    int nodeAc = nodeA < NNODES ? nodeA : NNODES - 1;

    // ---- phase 1: C1[16x64] = aggr[16x256] @ Ws[256x64] ----
    f32x4 zero = {0.f, 0.f, 0.f, 0.f};
    f32x4 acc1[4];
#pragma unroll
    for (int tt = 0; tt < 4; tt++) acc1[tt] = zero;
    const f16x8* WsV = (const f16x8*)WsP;
#pragma unroll
    for (int ks = 0; ks < 8; ks++) {
        f16x8 a = *(const f16x8*)(aggr16 + (size_t)nodeAc * 256 + ks * 32 + lg * 8);
#pragma unroll
        for (int tt = 0; tt < 4; tt++) {
            f16x8 b = WsV[(ks * 4 + tt) * 64 + l];
            acc1[tt] = __builtin_amdgcn_mfma_f32_16x16x32_f16(a, b, acc1[tt], 0, 0, 0);
        }
    }
    // bias + celu -> m_lds (transpose C-layout -> row-major rows)
#pragma unroll
    for (int tt = 0; tt < 4; tt++) {
        float bj = bvec[tt * 16 + ll];
#pragma unroll
        for (int i = 0; i < 4; i++) {
            float v = acc1[tt][i] + bj;
            v = v > 0.f ? v : (__expf(v) - 1.f);  // celu
            m_lds[w][lg * 4 + i][tt * 16 + ll] = (f16)v;
        }
    }
    asm volatile("s_waitcnt lgkmcnt(0)" ::: "memory");

    // ---- phase 2: gi = m@Wih^T, gh = h@Whh^T  (16x64 @ 64x192) ----
    f16x8 mf[2], hf[2];
#pragma unroll
    for (int ks = 0; ks < 2; ks++) {
        mf[ks] = *(const f16x8*)(&m_lds[w][ll][ks * 32 + lg * 8]);
        const float* hp = h_in + (size_t)nodeAc * 64 + ks * 32 + lg * 8;
        float4 h0 = *(const float4*)(hp);
        float4 h1 = *(const float4*)(hp + 4);
        f16x8 hh;
        hh[0] = (f16)h0.x; hh[1] = (f16)h0.y; hh[2] = (f16)h0.z; hh[3] = (f16)h0.w;
        hh[4] = (f16)h1.x; hh[5] = (f16)h1.y; hh[6] = (f16)h1.z; hh[7] = (f16)h1.w;
        hf[ks] = hh;
    }
    f32x4 accI[12], accH[12];
#pragma unroll
    for (int tt = 0; tt < 12; tt++) { accI[tt] = zero; accH[tt] = zero; }
    const f16x8* WiV = (const f16x8*)WihP;
    const f16x8* WhV = (const f16x8*)WhhP;
#pragma unroll
    for (int ks = 0; ks < 2; ks++) {
#pragma unroll
        for (int tt = 0; tt < 12; tt++) {
            f16x8 bi = WiV[(ks * 12 + tt) * 64 + l];
            accI[tt] = __builtin_amdgcn_mfma_f32_16x16x32_f16(mf[ks], bi, accI[tt], 0, 0, 0);
            f16x8 bh = WhV[(ks * 12 + tt) * 64 + l];
            accH[tt] = __builtin_amdgcn_mfma_f32_16x16x32_f16(hf[ks], bh, accH[tt], 0, 0, 0);
        }
    }

    // ---- phase 3: GRU elementwise + LayerNorm ----
    float bI[12], bH[12];
#pragma unroll
    for (int tt = 0; tt < 12; tt++) {
        bI[tt] = bih[ll + 16 * tt];
        bH[tt] = bhh[ll + 16 * tt];
    }
    float ga[4], be[4];
#pragma unroll
    for (int u = 0; u < 4; u++) { ga[u] = gamma[ll + 16 * u]; be[u] = beta[ll + 16 * u]; }
    float hnew[4][4];  // [i][u]
#pragma unroll
    for (int i = 0; i < 4; i++) {
        int node = nb + lg * 4 + i;
        int nc = node < NNODES ? node : NNODES - 1;
        const float* hrow = h_in + (size_t)nc * 64 + ll;
#pragma unroll
        for (int u = 0; u < 4; u++) {
            float hv = hrow[16 * u];
            float r = 1.f / (1.f + __expf(-(accI[u][i] + bI[u] + accH[u][i] + bH[u])));
            float z = 1.f / (1.f + __expf(-(accI[u + 4][i] + bI[u + 4] + accH[u + 4][i] + bH[u + 4])));
            float pre = accI[u + 8][i] + bI[u + 8] + r * (accH[u + 8][i] + bH[u + 8]);
            float e2 = __expf(2.f * pre);
            float nn = 1.f - 2.f / (e2 + 1.f);  // tanh, inf-safe
            hnew[i][u] = (1.f - z) * nn + z * hv;
        }
    }
#pragma unroll
    for (int i = 0; i < 4; i++) {
        float s = hnew[i][0] + hnew[i][1] + hnew[i][2] + hnew[i][3];
        float q = hnew[i][0] * hnew[i][0] + hnew[i][1] * hnew[i][1]
                + hnew[i][2] * hnew[i][2] + hnew[i][3] * hnew[i][3];
#pragma unroll
        for (int off = 1; off < 16; off <<= 1) {
            s += __shfl_xor(s, off, 64);
            q += __shfl_xor(q, off, 64);
        }
        float mu = s * (1.f / 64.f);
        float var = q * (1.f / 64.f) - mu * mu;
        float rstd = rsqrtf(var + 1e-5f);
        int node = nb + lg * 4 + i;
        if (node < NNODES) {
            float* ho = h_out + (size_t)node * 64 + ll;
            float* xo = xc_out + (size_t)node * 64 + ll;
#pragma unroll
            for (int u = 0; u < 4; u++) {
                ho[16 * u] = hnew[i][u];
                xo[16 * u] = (hnew[i][u] - mu) * rstd * ga[u] + be[u];
            }
        }
    }
}

// ---------------- launcher ----------------

extern "C" void kernel_launch(void* const* d_in, const int* in_sizes, int n_in,
                              void* d_out, int out_size, void* d_ws, size_t ws_size,
                              hipStream_t stream)
{
    const float* x         = (const float*)d_in[0];
    const int*   edge_index= (const int*)d_in[1];
    const float* edge_attr = (const float*)d_in[2];
    const float* Wn        = (const float*)d_in[3];
    const float* We        = (const float*)d_in[4];
    const float* Wa        = (const float*)d_in[5];
    const float* Ws        = (const float*)d_in[6];
    const float* bv        = (const float*)d_in[7];
    const float* Wih       = (const float*)d_in[8];
    const float* Whh       = (const float*)d_in[9];
    const float* bih       = (const float*)d_in[10];
    const float* bhh       = (const float*)d_in[11];
    const float* gamma     = (const float*)d_in[12];
    const float* beta      = (const float*)d_in[13];
    float* out = (float*)d_out;

    const int* src = edge_index;
    const int* dst = edge_index + NEDGES;

    char* w = (char*)d_ws;
    auto alloc = [&](size_t bytes) {
        char* p = w;
        w += (bytes + 255) & ~(size_t)255;
        return p;
    };
    f16*   xp16     = (f16*)alloc((size_t)NNODES * 256 * 2);
    f16*   aggr16   = (f16*)alloc((size_t)NNODES * 256 * 2);
    float* ae_csr   = (float*)alloc((size_t)NEDGES * 4 * 4);
    uint*  ea16_csr = (uint*)alloc((size_t)NEDGES * 8 * 4);
    float* hbuf     = (float*)alloc((size_t)NNODES * 64 * 4);
    float* aijI     = (float*)alloc((size_t)NNODES * 4 * 4);
    float* aijJ     = (float*)alloc((size_t)NNODES * 4 * 4);
    int*   counts   = (int*)alloc((size_t)NNODES * 4);
    int*   fill     = (int*)alloc((size_t)NNODES * 4);
    int*   row_ptr  = (int*)alloc((size_t)(NNODES + 1) * 4);
    int*   csr_src  = (int*)alloc((size_t)NEDGES * 4);
    float* wnwa0    = (float*)alloc(256 * 4);
    float* wnwa2    = (float*)alloc(256 * 4);
    float* wewa1    = (float*)alloc(64 * 4);
    uint*  WeP      = (uint*)alloc(2048 * 4);
    f16*   WsP      = (f16*)alloc(2048 * 8 * 2);
    f16*   WihP     = (f16*)alloc(1536 * 8 * 2);
    f16*   WhhP     = (f16*)alloc(1536 * 8 * 2);

    k_fold<<<1, 256, 0, stream>>>(Wn, We, Wa, Wih, Whh, Ws, wnwa0, wnwa2, wewa1,
                                  WeP, WsP, WihP, WhhP);
    hipMemsetAsync(counts, 0, (size_t)NNODES * 4, stream);
    hipMemsetAsync(fill, 0, (size_t)NNODES * 4, stream);
    k_hist<<<NEDGES / 256, 256, 0, stream>>>(dst, counts);
    k_scan<<<1, 1024, 0, stream>>>(counts, row_ptr, NNODES);
    k_scatter<<<NEDGES / 256, 256, 0, stream>>>(src, dst, edge_attr, wewa1,
                                                row_ptr, fill, csr_src,
                                                ae_csr, ea16_csr);

    for (int step = 0; step < 3; step++) {
        const float* xc_in = (step == 0) ? x : out;
        const float* h_in  = (step == 0) ? x : hbuf;
        k_xpaij<<<NNODES / 16, 256, 0, stream>>>(xc_in, Wn, wnwa0, wnwa2,
                                                 xp16, aijI, aijJ);
        k_node<<<NNODES / 4, 256, 0, stream>>>(row_ptr, csr_src, ae_csr, aijI,
                                               aijJ, xp16, ea16_csr, WeP, aggr16);
        k_post<<<(NNODES + 63) / 64, 256, 0, stream>>>(
            aggr16, WsP, bv, h_in, hbuf, WihP, WhhP, bih, bhh, gamma, beta, out);
    }
}